// Round 1
// baseline (2742.291 us; speedup 1.0000x reference)
//
#include <hip/hip_runtime.h>

#define Tn 512
#define Hn 1024
#define Fn 64
#define NTH 256

struct QParams {
  const float *x;
  const float *qw0, *qw1, *qw2, *qw3;
  const float *Wy_e, *by_e, *Wf_e, *bf_e, *Wi_e, *bi_e, *Wu_e, *bu_e, *Wo_e, *bo_e;
  const float *Wy_d, *by_d, *Wf_d, *bf_d, *Wi_d, *bi_d, *Wu_d, *bu_d, *Wo_d, *bo_d;
  const float *Wt, *bt;
  float *out;
};

__device__ __forceinline__ float sigf(float v) { return 1.f / (1.f + __expf(-v)); }
__device__ __forceinline__ float tanhfast(float v) {
  float w = fminf(fmaxf(2.f * v, -30.f), 30.f);
  float e = __expf(w);
  return (e - 1.f) / (e + 1.f);
}

// One LSTM scan. Per-block state: h in LDS, c in registers (4 per thread).
// Circuit expvals computed in closed form:
//   z0 = c1*c2*c3, z1 = c0*c1, z2 = c0*c1*c2, z3 = c0*c1*c2*c3,
//   with c_q = cos(y_q + w4[g][q]) expanded via angle-addition.
template <bool DEC>
__device__ void lstm_pass(int b, int tid, int lane, int wid,
                          const float *__restrict__ x, const float *henc,
                          const float *__restrict__ Wy, const float *__restrict__ by,
                          const float *__restrict__ Wf, const float *__restrict__ bf,
                          const float *__restrict__ Wi, const float *__restrict__ bi,
                          const float *__restrict__ Wu, const float *__restrict__ bu,
                          const float *__restrict__ Wo, const float *__restrict__ bo,
                          const float (&cw)[4][4], const float (&sw)[4][4],
                          float *h_lds, float4 *red, float (&c_reg)[4]) {
  const int K = DEC ? (Hn + 1) : (Hn + Fn);
  for (int t = 0; t < Tn; ++t) {
    // ---- prefetch this step's gate weights/biases into registers.
    // Issued at loop top so global latency overlaps the y phase below.
    float wF[4][4], wI[4][4], wU[4][4], wO[4][4];
    float bF[4], bI[4], bU[4], bO[4];
#pragma unroll
    for (int m = 0; m < 4; ++m) {
      const int j = tid + NTH * m;
      const int gb = t * (4 * Hn) + j;
#pragma unroll
      for (int n = 0; n < 4; ++n) {
        wF[n][m] = Wf[gb + n * Hn];
        wI[n][m] = Wi[gb + n * Hn];
        wU[n][m] = Wu[gb + n * Hn];
        wO[n][m] = Wo[gb + n * Hn];
      }
      bF[m] = bf[t * Hn + j];
      bI[m] = bi[t * Hn + j];
      bU[m] = bu[t * Hn + j];
      bO[m] = bo[t * Hn + j];
    }

    // ---- y = [h, x_t] @ Wy[t] + by[t]   (4 outputs)
    float a0 = 0.f, a1 = 0.f, a2 = 0.f, a3 = 0.f;
#pragma unroll
    for (int m = 0; m < 4; ++m) {
      const int k = tid + NTH * m;
      const float hv = h_lds[k];
      const float4 w = *(const float4 *)(Wy + ((size_t)t * K + k) * 4);
      a0 = fmaf(hv, w.x, a0);
      a1 = fmaf(hv, w.y, a1);
      a2 = fmaf(hv, w.z, a2);
      a3 = fmaf(hv, w.w, a3);
    }
    if (!DEC) {
      if (tid < Fn) {
        const float xv = x[((size_t)b * Tn + t) * Fn + tid];
        const float4 w = *(const float4 *)(Wy + ((size_t)t * K + Hn + tid) * 4);
        a0 = fmaf(xv, w.x, a0);
        a1 = fmaf(xv, w.y, a1);
        a2 = fmaf(xv, w.z, a2);
        a3 = fmaf(xv, w.w, a3);
      }
    } else {
      if (tid == 0) {
        const float xv = henc[t];
        const float4 w = *(const float4 *)(Wy + ((size_t)t * K + Hn) * 4);
        a0 = fmaf(xv, w.x, a0);
        a1 = fmaf(xv, w.y, a1);
        a2 = fmaf(xv, w.z, a2);
        a3 = fmaf(xv, w.w, a3);
      }
    }
    // wave reduce (64 lanes)
#pragma unroll
    for (int s = 1; s < 64; s <<= 1) {
      a0 += __shfl_xor(a0, s);
      a1 += __shfl_xor(a1, s);
      a2 += __shfl_xor(a2, s);
      a3 += __shfl_xor(a3, s);
    }
    if (lane == 0) red[wid] = make_float4(a0, a1, a2, a3);
    __syncthreads();
    const float4 r0 = red[0], r1 = red[1], r2 = red[2], r3 = red[3];
    const float y0 = r0.x + r1.x + r2.x + r3.x + by[t * 4 + 0];
    const float y1 = r0.y + r1.y + r2.y + r3.y + by[t * 4 + 1];
    const float y2 = r0.z + r1.z + r2.z + r3.z + by[t * 4 + 2];
    const float y3 = r0.w + r1.w + r2.w + r3.w + by[t * 4 + 3];

    // ---- circuit expvals + activations (redundant per thread, no comms)
    float sy[4], cy[4];
    __sincosf(y0, &sy[0], &cy[0]);
    __sincosf(y1, &sy[1], &cy[1]);
    __sincosf(y2, &sy[2], &cy[2]);
    __sincosf(y3, &sy[3], &cy[3]);
    float act[4][4];
#pragma unroll
    for (int g = 0; g < 4; ++g) {
      const float c0 = cy[0] * cw[g][0] - sy[0] * sw[g][0];
      const float c1 = cy[1] * cw[g][1] - sy[1] * sw[g][1];
      const float c2 = cy[2] * cw[g][2] - sy[2] * sw[g][2];
      const float c3 = cy[3] * cw[g][3] - sy[3] * sw[g][3];
      const float z0 = c1 * c2 * c3;
      const float z1 = c0 * c1;
      const float z2 = z1 * c2;
      const float z3 = z2 * c3;
      if (g == 2) {
        act[g][0] = tanhfast(z0);
        act[g][1] = tanhfast(z1);
        act[g][2] = tanhfast(z2);
        act[g][3] = tanhfast(z3);
      } else {
        act[g][0] = sigf(z0);
        act[g][1] = sigf(z1);
        act[g][2] = sigf(z2);
        act[g][3] = sigf(z3);
      }
    }

    // ---- gate matvecs (K=4) + state update; 4 h-outputs per thread
#pragma unroll
    for (int m = 0; m < 4; ++m) {
      float fv = bF[m], iv = bI[m], uv = bU[m], ov = bO[m];
#pragma unroll
      for (int n = 0; n < 4; ++n) {
        fv = fmaf(act[0][n], wF[n][m], fv);
        iv = fmaf(act[1][n], wI[n][m], iv);
        uv = fmaf(act[2][n], wU[n][m], uv);
        ov = fmaf(act[3][n], wO[n][m], ov);
      }
      const float cn = fmaf(fv, c_reg[m], iv * uv);
      c_reg[m] = cn;
      h_lds[tid + NTH * m] = ov * tanhfast(cn);
    }
    __syncthreads();
  }
}

__global__ __launch_bounds__(NTH, 1) void qlstm_ae_kernel(QParams p) {
  const int b = blockIdx.x;
  const int tid = threadIdx.x;
  const int lane = tid & 63;
  const int wid = tid >> 6;

  __shared__ float h_lds[Hn];
  __shared__ float henc[Hn];
  __shared__ float4 red[4];

  // w4 angle tables (cos/sin), computed once
  float cw[4][4], sw[4][4];
  {
    const float *qw[4] = {p.qw0, p.qw1, p.qw2, p.qw3};
#pragma unroll
    for (int g = 0; g < 4; ++g)
#pragma unroll
      for (int q = 0; q < 4; ++q) {
        const float w = qw[g][q];
        cw[g][q] = cosf(w);
        sw[g][q] = sinf(w);
      }
  }

  float c_reg[4] = {0.f, 0.f, 0.f, 0.f};
#pragma unroll
  for (int m = 0; m < 4; ++m) h_lds[tid + NTH * m] = 0.f;
  __syncthreads();

  // encoder: x (B,T,64)
  lstm_pass<false>(b, tid, lane, wid, p.x, nullptr, p.Wy_e, p.by_e, p.Wf_e,
                   p.bf_e, p.Wi_e, p.bi_e, p.Wu_e, p.bu_e, p.Wo_e, p.bo_e, cw,
                   sw, h_lds, red, c_reg);

  // h_enc -> henc; reset state
#pragma unroll
  for (int m = 0; m < 4; ++m) {
    henc[tid + NTH * m] = h_lds[tid + NTH * m];
    h_lds[tid + NTH * m] = 0.f;
    c_reg[m] = 0.f;
  }
  __syncthreads();

  // decoder: x2[b,t,0] = h_enc[b,t]
  lstm_pass<true>(b, tid, lane, wid, nullptr, henc, p.Wy_d, p.by_d, p.Wf_d,
                  p.bf_d, p.Wi_d, p.bi_d, p.Wu_d, p.bu_d, p.Wo_d, p.bo_d, cw,
                  sw, h_lds, red, c_reg);

  // ---- target = h_dec @ Wt + bt ; out shape (B, T, 1)
  for (int t2 = tid; t2 < Tn; t2 += NTH) {
    float acc = p.bt[t2];
#pragma unroll 8
    for (int j = 0; j < Hn; ++j) acc = fmaf(h_lds[j], p.Wt[j * Tn + t2], acc);
    p.out[(size_t)b * Tn + t2] = acc;
  }
}

extern "C" void kernel_launch(void *const *d_in, const int *in_sizes, int n_in,
                              void *d_out, int out_size, void *d_ws,
                              size_t ws_size, hipStream_t stream) {
  QParams p;
  p.x = (const float *)d_in[0];
  p.qw0 = (const float *)d_in[1];
  p.qw1 = (const float *)d_in[2];
  p.qw2 = (const float *)d_in[3];
  p.qw3 = (const float *)d_in[4];
  p.Wy_e = (const float *)d_in[5];
  p.by_e = (const float *)d_in[6];
  p.Wf_e = (const float *)d_in[7];
  p.bf_e = (const float *)d_in[8];
  p.Wi_e = (const float *)d_in[9];
  p.bi_e = (const float *)d_in[10];
  p.Wu_e = (const float *)d_in[11];
  p.bu_e = (const float *)d_in[12];
  p.Wo_e = (const float *)d_in[13];
  p.bo_e = (const float *)d_in[14];
  p.Wy_d = (const float *)d_in[15];
  p.by_d = (const float *)d_in[16];
  p.Wf_d = (const float *)d_in[17];
  p.bf_d = (const float *)d_in[18];
  p.Wi_d = (const float *)d_in[19];
  p.bi_d = (const float *)d_in[20];
  p.Wu_d = (const float *)d_in[21];
  p.bu_d = (const float *)d_in[22];
  p.Wo_d = (const float *)d_in[23];
  p.bo_d = (const float *)d_in[24];
  p.Wt = (const float *)d_in[25];
  p.bt = (const float *)d_in[26];
  p.out = (float *)d_out;

  hipLaunchKernelGGL(qlstm_ae_kernel, dim3(16), dim3(NTH), 0, stream, p);
}

// Round 2
// 2140.868 us; speedup vs baseline: 1.2809x; 1.2809x over previous
//
#include <hip/hip_runtime.h>

#define Tn 512
#define Hn 1024
#define Fn 64
#define NTH 1024

struct QParams {
  const float *x;
  const float *qw0, *qw1, *qw2, *qw3;
  const float *Wy_e, *by_e, *Wf_e, *bf_e, *Wi_e, *bi_e, *Wu_e, *bu_e, *Wo_e, *bo_e;
  const float *Wy_d, *by_d, *Wf_d, *bf_d, *Wi_d, *bi_d, *Wu_d, *bu_d, *Wo_d, *bo_d;
  const float *Wt, *bt;
  float *out;
};

// Raw barrier: drain LDS/ds ops only; vmem (global) loads stay in flight
// across it (T4 counted-vmcnt semantics -- the compiler waits on the weight
// loads only at their use in phase C, one step after issue).
#define BAR()                                                                  \
  do {                                                                         \
    asm volatile("s_waitcnt lgkmcnt(0)" ::: "memory");                         \
    __builtin_amdgcn_s_barrier();                                              \
    asm volatile("" ::: "memory");                                             \
  } while (0)

__device__ __forceinline__ float fast_sig(float x) {
  return __builtin_amdgcn_rcpf(1.f + __expf(-x));
}
__device__ __forceinline__ float fast_tanh(float x) {
  // tanh(x) = 1 - 2/(exp(2x)+1); exp->inf => 1, exp->0 => -1 (no NaN)
  return fmaf(-2.f, __builtin_amdgcn_rcpf(__expf(2.f * x) + 1.f), 1.f);
}

// Per-thread register buffer for one timestep's weights (double-buffered).
struct WB {
  float w[16];  // [g*4+n] = W{f,i,u,o}[t][n][tid]
  float bb[4];  // b{f,i,u,o}[t][tid]
  float4 wy;    // Wy[t][tid][0..3]
  float4 wyx;   // enc tid<64: Wy[t][1024+tid]; dec tid==0: Wy[t][1024]
  float xv;     // enc tid<64: x[b][t][tid]
};

template <bool DEC>
__device__ __forceinline__ void
pf(WB &d, int t, int b, int tid, const float *__restrict__ x,
   const float *__restrict__ Wy, const float *__restrict__ Wf,
   const float *__restrict__ bf, const float *__restrict__ Wi,
   const float *__restrict__ bi, const float *__restrict__ Wu,
   const float *__restrict__ bu, const float *__restrict__ Wo,
   const float *__restrict__ bo) {
  const int K = DEC ? (Hn + 1) : (Hn + Fn);
  const size_t go = (size_t)t * (4 * Hn) + tid;
#pragma unroll
  for (int n = 0; n < 4; ++n) {
    d.w[0 * 4 + n] = Wf[go + n * Hn];
    d.w[1 * 4 + n] = Wi[go + n * Hn];
    d.w[2 * 4 + n] = Wu[go + n * Hn];
    d.w[3 * 4 + n] = Wo[go + n * Hn];
  }
  const size_t bofs = (size_t)t * Hn + tid;
  d.bb[0] = bf[bofs];
  d.bb[1] = bi[bofs];
  d.bb[2] = bu[bofs];
  d.bb[3] = bo[bofs];
  d.wy = *(const float4 *)(Wy + ((size_t)t * K + tid) * 4);
  if (!DEC) {
    if (tid < Fn) {
      d.wyx = *(const float4 *)(Wy + ((size_t)t * K + Hn + tid) * 4);
      d.xv = x[((size_t)b * Tn + t) * Fn + tid];
    }
  } else {
    if (tid == 0) d.wyx = *(const float4 *)(Wy + ((size_t)t * K + Hn) * 4);
  }
}

template <bool DEC>
__device__ __forceinline__ void
halfstep(int t, int tn, const WB &rd, WB &wr, int b, int tid, int lane, int wid,
         const float *__restrict__ x, const float *__restrict__ Wy,
         const float *__restrict__ Wf, const float *__restrict__ bf,
         const float *__restrict__ Wi, const float *__restrict__ bi,
         const float *__restrict__ Wu, const float *__restrict__ bu,
         const float *__restrict__ Wo, const float *__restrict__ bo,
         float *h_lds, const float *henc, const float *by_l, float4 *red,
         float4 *acts4, const float4 *w4s, float &c_reg) {
  // ---------- phase A: partial y = [h, x_t] @ Wy[t]  (this wave's 64 elems)
  {
    const float hv = h_lds[tid];
    float a0 = hv * rd.wy.x, a1 = hv * rd.wy.y, a2 = hv * rd.wy.z,
          a3 = hv * rd.wy.w;
    if (!DEC) {
      if (tid < Fn) {
        a0 = fmaf(rd.xv, rd.wyx.x, a0);
        a1 = fmaf(rd.xv, rd.wyx.y, a1);
        a2 = fmaf(rd.xv, rd.wyx.z, a2);
        a3 = fmaf(rd.xv, rd.wyx.w, a3);
      }
    } else {
      if (tid == 0) {
        const float xv = henc[t];
        a0 = fmaf(xv, rd.wyx.x, a0);
        a1 = fmaf(xv, rd.wyx.y, a1);
        a2 = fmaf(xv, rd.wyx.z, a2);
        a3 = fmaf(xv, rd.wyx.w, a3);
      }
    }
#pragma unroll
    for (int s = 1; s < 64; s <<= 1) {
      a0 += __shfl_xor(a0, s);
      a1 += __shfl_xor(a1, s);
      a2 += __shfl_xor(a2, s);
      a3 += __shfl_xor(a3, s);
    }
    if (lane == 0) red[wid] = make_float4(a0, a1, a2, a3);
  }
  // issue next step's weight loads; they stay in flight across the barriers
  pf<DEC>(wr, tn, b, tid, x, Wy, Wf, bf, Wi, bi, Wu, bu, Wo, bo);
  BAR();
  // ---------- phase B: finalize y, circuit, activations (waves 0-3 = gates)
  if (wid < 4) {
    float4 v = red[lane & 15];
#pragma unroll
    for (int s = 1; s < 16; s <<= 1) {
      v.x += __shfl_xor(v.x, s);
      v.y += __shfl_xor(v.y, s);
      v.z += __shfl_xor(v.z, s);
      v.w += __shfl_xor(v.w, s);
    }
    const float4 byt = ((const float4 *)by_l)[t];
    const float4 wq = w4s[wid];
    // closed-form circuit: <Z0>=c1c2c3, <Z1>=c0c1, <Z2>=c0c1c2, <Z3>=c0c1c2c3
    const float c0 = __cosf(v.x + byt.x + wq.x);
    const float c1 = __cosf(v.y + byt.y + wq.y);
    const float c2 = __cosf(v.z + byt.z + wq.z);
    const float c3 = __cosf(v.w + byt.w + wq.w);
    const float t12 = c1 * c2;
    const float z0 = t12 * c3;
    const float z1 = c0 * c1;
    const float z2 = c0 * t12;
    const float z3 = z2 * c3;
    float4 a;
    if (wid == 2)
      a = make_float4(fast_tanh(z0), fast_tanh(z1), fast_tanh(z2),
                      fast_tanh(z3));
    else
      a = make_float4(fast_sig(z0), fast_sig(z1), fast_sig(z2), fast_sig(z3));
    if (lane == 0) acts4[wid] = a;
  }
  BAR();
  // ---------- phase C: gate matvec (K=4) + state update, 1 output/thread
  {
    const float4 af = acts4[0], ai = acts4[1], au = acts4[2], ao = acts4[3];
    float fv = rd.bb[0], iv = rd.bb[1], uv = rd.bb[2], ov = rd.bb[3];
    fv = fmaf(af.x, rd.w[0], fv);
    fv = fmaf(af.y, rd.w[1], fv);
    fv = fmaf(af.z, rd.w[2], fv);
    fv = fmaf(af.w, rd.w[3], fv);
    iv = fmaf(ai.x, rd.w[4], iv);
    iv = fmaf(ai.y, rd.w[5], iv);
    iv = fmaf(ai.z, rd.w[6], iv);
    iv = fmaf(ai.w, rd.w[7], iv);
    uv = fmaf(au.x, rd.w[8], uv);
    uv = fmaf(au.y, rd.w[9], uv);
    uv = fmaf(au.z, rd.w[10], uv);
    uv = fmaf(au.w, rd.w[11], uv);
    ov = fmaf(ao.x, rd.w[12], ov);
    ov = fmaf(ao.y, rd.w[13], ov);
    ov = fmaf(ao.z, rd.w[14], ov);
    ov = fmaf(ao.w, rd.w[15], ov);
    const float cn = fmaf(fv, c_reg, iv * uv);
    c_reg = cn;
    h_lds[tid] = ov * fast_tanh(cn);
  }
  BAR();
}

template <bool DEC>
__device__ void
lstm_pass(int b, int tid, int lane, int wid, const float *__restrict__ x,
          const float *__restrict__ Wy, const float *__restrict__ by,
          const float *__restrict__ Wf, const float *__restrict__ bf,
          const float *__restrict__ Wi, const float *__restrict__ bi,
          const float *__restrict__ Wu, const float *__restrict__ bu,
          const float *__restrict__ Wo, const float *__restrict__ bo,
          float *h_lds, const float *henc, float *by_l, float4 *red,
          float4 *acts4, const float4 *w4s, float &c_reg) {
  // stage by[] (tiny, avoids a scalarized s_load being drained at lgkmcnt(0))
#pragma unroll
  for (int i = 0; i < (Tn * 4) / NTH; ++i) by_l[tid + i * NTH] = by[tid + i * NTH];
  __syncthreads();
  WB bufA, bufB;
  pf<DEC>(bufA, 0, b, tid, x, Wy, Wf, bf, Wi, bi, Wu, bu, Wo, bo);
  for (int t = 0; t < Tn; t += 2) {
    halfstep<DEC>(t, t + 1, bufA, bufB, b, tid, lane, wid, x, Wy, Wf, bf, Wi,
                  bi, Wu, bu, Wo, bo, h_lds, henc, by_l, red, acts4, w4s,
                  c_reg);
    halfstep<DEC>(t + 1, (t + 2 < Tn) ? (t + 2) : (Tn - 1), bufB, bufA, b, tid,
                  lane, wid, x, Wy, Wf, bf, Wi, bi, Wu, bu, Wo, bo, h_lds,
                  henc, by_l, red, acts4, w4s, c_reg);
  }
}

__global__ __launch_bounds__(NTH, 1) void qlstm_ae_kernel(QParams p) {
  const int b = blockIdx.x;
  const int tid = threadIdx.x;
  const int lane = tid & 63;
  const int wid = tid >> 6;

  __shared__ __align__(16) float h_lds[Hn];
  __shared__ __align__(16) float henc_s[Hn];
  __shared__ __align__(16) float by_l[Tn * 4];
  __shared__ float4 red[16];
  __shared__ float4 acts4[4];
  __shared__ float4 w4s[4];

  if (tid == 0)
    w4s[0] = *(const float4 *)p.qw0;
  else if (tid == 1)
    w4s[1] = *(const float4 *)p.qw1;
  else if (tid == 2)
    w4s[2] = *(const float4 *)p.qw2;
  else if (tid == 3)
    w4s[3] = *(const float4 *)p.qw3;

  float c_reg = 0.f;
  h_lds[tid] = 0.f;
  // visibility of h_lds/w4s covered by the __syncthreads inside lstm_pass

  lstm_pass<false>(b, tid, lane, wid, p.x, p.Wy_e, p.by_e, p.Wf_e, p.bf_e,
                   p.Wi_e, p.bi_e, p.Wu_e, p.bu_e, p.Wo_e, p.bo_e, h_lds,
                   henc_s, by_l, red, acts4, w4s, c_reg);

  // h_enc -> henc_s ; reset state (visibility covered by decoder's staging sync)
  henc_s[tid] = h_lds[tid];
  h_lds[tid] = 0.f;
  c_reg = 0.f;

  lstm_pass<true>(b, tid, lane, wid, nullptr, p.Wy_d, p.by_d, p.Wf_d, p.bf_d,
                  p.Wi_d, p.bi_d, p.Wu_d, p.bu_d, p.Wo_d, p.bo_d, h_lds,
                  henc_s, by_l, red, acts4, w4s, c_reg);

  // ---- target = h_dec @ Wt + bt ; out (B, T, 1)
  if (tid < Tn) {
    float acc = p.bt[tid];
    const float4 *h4 = (const float4 *)h_lds;
#pragma unroll 4
    for (int j4 = 0; j4 < Hn / 4; ++j4) {
      const float4 hv = h4[j4];
      acc = fmaf(hv.x, p.Wt[(j4 * 4 + 0) * Tn + tid], acc);
      acc = fmaf(hv.y, p.Wt[(j4 * 4 + 1) * Tn + tid], acc);
      acc = fmaf(hv.z, p.Wt[(j4 * 4 + 2) * Tn + tid], acc);
      acc = fmaf(hv.w, p.Wt[(j4 * 4 + 3) * Tn + tid], acc);
    }
    p.out[(size_t)b * Tn + tid] = acc;
  }
}

extern "C" void kernel_launch(void *const *d_in, const int *in_sizes, int n_in,
                              void *d_out, int out_size, void *d_ws,
                              size_t ws_size, hipStream_t stream) {
  QParams p;
  p.x = (const float *)d_in[0];
  p.qw0 = (const float *)d_in[1];
  p.qw1 = (const float *)d_in[2];
  p.qw2 = (const float *)d_in[3];
  p.qw3 = (const float *)d_in[4];
  p.Wy_e = (const float *)d_in[5];
  p.by_e = (const float *)d_in[6];
  p.Wf_e = (const float *)d_in[7];
  p.bf_e = (const float *)d_in[8];
  p.Wi_e = (const float *)d_in[9];
  p.bi_e = (const float *)d_in[10];
  p.Wu_e = (const float *)d_in[11];
  p.bu_e = (const float *)d_in[12];
  p.Wo_e = (const float *)d_in[13];
  p.bo_e = (const float *)d_in[14];
  p.Wy_d = (const float *)d_in[15];
  p.by_d = (const float *)d_in[16];
  p.Wf_d = (const float *)d_in[17];
  p.bf_d = (const float *)d_in[18];
  p.Wi_d = (const float *)d_in[19];
  p.bi_d = (const float *)d_in[20];
  p.Wu_d = (const float *)d_in[21];
  p.bu_d = (const float *)d_in[22];
  p.Wo_d = (const float *)d_in[23];
  p.bo_d = (const float *)d_in[24];
  p.Wt = (const float *)d_in[25];
  p.bt = (const float *)d_in[26];
  p.out = (float *)d_out;

  hipLaunchKernelGGL(qlstm_ae_kernel, dim3(16), dim3(NTH), 0, stream, p);
}

// Round 3
// 1335.227 us; speedup vs baseline: 2.0538x; 1.6034x over previous
//
#include <hip/hip_runtime.h>

#define Tn 512
#define Hn 1024
#define Fn 64
#define NTH 512
#define NW (NTH / 64)

struct QParams {
  const float *x;
  const float *qw0, *qw1, *qw2, *qw3;
  const float *Wy_e, *by_e, *Wf_e, *bf_e, *Wi_e, *bi_e, *Wu_e, *bu_e, *Wo_e, *bo_e;
  const float *Wy_d, *by_d, *Wf_d, *bf_d, *Wi_d, *bi_d, *Wu_d, *bu_d, *Wo_d, *bo_d;
  const float *Wt, *bt;
  float *out;
};

// Raw barrier: drain LDS ops only; global (vmem) weight prefetch stays in
// flight across it (counted-vmcnt semantics left to the compiler).
#define BAR()                                                                  \
  do {                                                                         \
    asm volatile("s_waitcnt lgkmcnt(0)" ::: "memory");                         \
    __builtin_amdgcn_s_barrier();                                              \
    asm volatile("" ::: "memory");                                             \
  } while (0)

template <int CTRL, int RM, int BM, bool BC>
__device__ __forceinline__ float dppadd(float x) {
  int t = __builtin_amdgcn_update_dpp(0, __builtin_bit_cast(int, x), CTRL, RM,
                                      BM, BC);
  return x + __builtin_bit_cast(float, t);
}
template <int CTRL>
__device__ __forceinline__ float dppmov(float x) {
  int t = __builtin_amdgcn_update_dpp(0, __builtin_bit_cast(int, x), CTRL, 0xF,
                                      0xF, true);
  return __builtin_bit_cast(float, t);
}

// 64-lane sum -> lane 63 (VALU-latency DPP butterfly, no LDS pipe)
__device__ __forceinline__ float wave_sum63(float x) {
  x = dppadd<0xB1, 0xF, 0xF, true>(x);   // quad_perm [1,0,3,2]  (xor 1)
  x = dppadd<0x4E, 0xF, 0xF, true>(x);   // quad_perm [2,3,0,1]  (xor 2)
  x = dppadd<0x141, 0xF, 0xF, true>(x);  // row_half_mirror      (pairs 0-3/4-7)
  x = dppadd<0x140, 0xF, 0xF, true>(x);  // row_mirror           (pairs 8-halves)
  x = dppadd<0x142, 0xA, 0xF, false>(x); // row_bcast15 -> rows 1,3
  x = dppadd<0x143, 0xC, 0xF, false>(x); // row_bcast31 -> rows 2,3
  return x;                              // lane 63 = total
}
// all-lanes sum over groups of 8 (lane i holds v[i&7])
__device__ __forceinline__ float sum8_all(float x) {
  x = dppadd<0xB1, 0xF, 0xF, true>(x);
  x = dppadd<0x4E, 0xF, 0xF, true>(x);
  x = dppadd<0x141, 0xF, 0xF, true>(x);
  return x;
}

__device__ __forceinline__ float tanhc(float c) {
  // tanh(c) = 1 - 2/(exp2(c*2*log2e)+1); saturates cleanly, no NaN
  float e = __builtin_amdgcn_exp2f(c * 2.885390081777927f);
  return fmaf(-2.f, __builtin_amdgcn_rcpf(e + 1.f), 1.f);
}

// Per-thread double-buffered weight registers for one timestep.
struct WB {
  float w[32];    // [e*16 + g*4 + n] = W_g[t][n][tid + e*512]
  float bb[8];    // [e*4 + g]
  float4 wy0, wy1; // Wy[t][tid], Wy[t][tid+512]
  float4 wyx;      // enc tid<64: Wy[t][1024+tid]; dec tid==0: Wy[t][1024]
  float xv;        // enc tid<64: x[b][t][tid]
};

template <bool DEC>
__device__ __forceinline__ WB
pf(int t, int b, int tid, const float *__restrict__ x,
   const float *__restrict__ Wy, const float *__restrict__ Wf,
   const float *__restrict__ bfp, const float *__restrict__ Wi,
   const float *__restrict__ bip, const float *__restrict__ Wu,
   const float *__restrict__ bup, const float *__restrict__ Wo,
   const float *__restrict__ bop) {
  WB d;
  const int K = DEC ? (Hn + 1) : (Hn + Fn);
  const int g0 = t * 4096 + tid;
#pragma unroll
  for (int e = 0; e < 2; ++e) {
    const int ge = g0 + e * 512;
#pragma unroll
    for (int n = 0; n < 4; ++n) {
      d.w[e * 16 + 0 * 4 + n] = Wf[ge + n * 1024];
      d.w[e * 16 + 1 * 4 + n] = Wi[ge + n * 1024];
      d.w[e * 16 + 2 * 4 + n] = Wu[ge + n * 1024];
      d.w[e * 16 + 3 * 4 + n] = Wo[ge + n * 1024];
    }
    const int be = t * 1024 + tid + e * 512;
    d.bb[e * 4 + 0] = bfp[be];
    d.bb[e * 4 + 1] = bip[be];
    d.bb[e * 4 + 2] = bup[be];
    d.bb[e * 4 + 3] = bop[be];
  }
  d.wy0 = *(const float4 *)(Wy + (t * K + tid) * 4);
  d.wy1 = *(const float4 *)(Wy + (t * K + tid + 512) * 4);
  if (!DEC) {
    if (tid < Fn) {
      d.wyx = *(const float4 *)(Wy + (t * K + Hn + tid) * 4);
      d.xv = x[(b * Tn + t) * Fn + tid];
    }
  } else {
    if (tid == 0) d.wyx = *(const float4 *)(Wy + (t * K + Hn) * 4);
  }
  return d;
}

struct LaneCtx {
  int tid, lane, wid;
  bool q1, q2;       // lane&1, lane&2  (qubit select)
  float w4lane;      // w4[g][q] for g=(lane>>2)&3, q=lane&3
  float mlane, alane, klane; // act = fma(sig(m*z), m, 1-m); k = -m*log2e
};

template <bool DEC, int PAR>
__device__ __forceinline__ void
step(int t, int tn, const WB &rd, WB &wr, int b, const LaneCtx &L,
     const float *__restrict__ x, const float *__restrict__ Wy,
     const float *__restrict__ Wf, const float *__restrict__ bfp,
     const float *__restrict__ Wi, const float *__restrict__ bip,
     const float *__restrict__ Wu, const float *__restrict__ bup,
     const float *__restrict__ Wo, const float *__restrict__ bop,
     float4 (*red4)[NW], const float *by_l, const float *henc_s,
     float &h0, float &h1, float &c0, float &c1) {
  // ---------- phase A: y partials + DPP reduce + red write
  float a0 = h0 * rd.wy0.x, a1 = h0 * rd.wy0.y, a2 = h0 * rd.wy0.z,
        a3 = h0 * rd.wy0.w;
  a0 = fmaf(h1, rd.wy1.x, a0);
  a1 = fmaf(h1, rd.wy1.y, a1);
  a2 = fmaf(h1, rd.wy1.z, a2);
  a3 = fmaf(h1, rd.wy1.w, a3);
  if (!DEC) {
    if (L.tid < Fn) {
      a0 = fmaf(rd.xv, rd.wyx.x, a0);
      a1 = fmaf(rd.xv, rd.wyx.y, a1);
      a2 = fmaf(rd.xv, rd.wyx.z, a2);
      a3 = fmaf(rd.xv, rd.wyx.w, a3);
    }
  } else {
    if (L.tid == 0) {
      const float xv = henc_s[t];
      a0 = fmaf(xv, rd.wyx.x, a0);
      a1 = fmaf(xv, rd.wyx.y, a1);
      a2 = fmaf(xv, rd.wyx.z, a2);
      a3 = fmaf(xv, rd.wyx.w, a3);
    }
  }
  a0 = wave_sum63(a0);
  a1 = wave_sum63(a1);
  a2 = wave_sum63(a2);
  a3 = wave_sum63(a3);
  if (L.lane == 63) red4[PAR][L.wid] = make_float4(a0, a1, a2, a3);

  // issue next step's weight loads; they stay in flight across the barrier
  wr = pf<DEC>(tn, b, L.tid, x, Wy, Wf, bfp, Wi, bip, Wu, bup, Wo, bop);

  BAR();

  // ---------- phase B: finalize y (all lanes), circuit lane-parallel
  float4 rv = red4[PAR][L.lane & 7];
  const float byq = by_l[t * 4 + (L.lane & 3)];
  float y0 = sum8_all(rv.x), y1 = sum8_all(rv.y), y2 = sum8_all(rv.z),
        y3 = sum8_all(rv.w);
  const float yq = L.q2 ? (L.q1 ? y3 : y2) : (L.q1 ? y1 : y0);
  const float ang = yq + byq + L.w4lane;
  const float cc = __cosf(ang);
  // quad products: z0=c1c2c3, z1=c0c1, z2=c0c1c2, z3=c0c1c2c3
  const float t1 = dppmov<0xB1>(cc); // c_{q^1}
  const float d1 = cc * t1;          // pair product
  const float t2 = dppmov<0x4E>(d1); // other pair's product
  const float d2 = d1 * t2;          // full product
  const float zu = t1 * t2;          // lane q=0: c1*(c2c3)
  const float zv = cc * t2;          // lane q=2: c2*(c0c1)
  const float z = L.q2 ? (L.q1 ? d2 : zv) : (L.q1 ? d1 : zu);
  // act: g!=2 -> sigmoid(z); g==2 -> tanh(z) = 2*sig(2z)-1
  const float s =
      __builtin_amdgcn_rcpf(1.f + __builtin_amdgcn_exp2f(L.klane * z));
  const float act = fmaf(s, L.mlane, L.alane);
#define RL(n)                                                                  \
  __builtin_bit_cast(float,                                                    \
                     __builtin_amdgcn_readlane(__builtin_bit_cast(int, act), n))
  const float f0 = RL(0), f1 = RL(1), f2 = RL(2), f3 = RL(3);
  const float i0 = RL(4), i1 = RL(5), i2 = RL(6), i3 = RL(7);
  const float u0 = RL(8), u1 = RL(9), u2 = RL(10), u3 = RL(11);
  const float o0 = RL(12), o1 = RL(13), o2 = RL(14), o3 = RL(15);
#undef RL

  // ---------- phase C: gate matvecs (K=4) + state update, 2 elems/thread
#pragma unroll
  for (int e = 0; e < 2; ++e) {
    float fv = rd.bb[e * 4 + 0], iv = rd.bb[e * 4 + 1], uv = rd.bb[e * 4 + 2],
          ov = rd.bb[e * 4 + 3];
    fv = fmaf(f0, rd.w[e * 16 + 0], fv);
    fv = fmaf(f1, rd.w[e * 16 + 1], fv);
    fv = fmaf(f2, rd.w[e * 16 + 2], fv);
    fv = fmaf(f3, rd.w[e * 16 + 3], fv);
    iv = fmaf(i0, rd.w[e * 16 + 4], iv);
    iv = fmaf(i1, rd.w[e * 16 + 5], iv);
    iv = fmaf(i2, rd.w[e * 16 + 6], iv);
    iv = fmaf(i3, rd.w[e * 16 + 7], iv);
    uv = fmaf(u0, rd.w[e * 16 + 8], uv);
    uv = fmaf(u1, rd.w[e * 16 + 9], uv);
    uv = fmaf(u2, rd.w[e * 16 + 10], uv);
    uv = fmaf(u3, rd.w[e * 16 + 11], uv);
    ov = fmaf(o0, rd.w[e * 16 + 12], ov);
    ov = fmaf(o1, rd.w[e * 16 + 13], ov);
    ov = fmaf(o2, rd.w[e * 16 + 14], ov);
    ov = fmaf(o3, rd.w[e * 16 + 15], ov);
    float &cr = e ? c1 : c0;
    float &hr = e ? h1 : h0;
    const float cn = fmaf(fv, cr, iv * uv);
    cr = cn;
    hr = ov * tanhc(cn);
  }
}

template <bool DEC>
__device__ void lstm_pass(int b, const LaneCtx &L, const float *__restrict__ x,
                          const float *__restrict__ Wy,
                          const float *__restrict__ by,
                          const float *__restrict__ Wf,
                          const float *__restrict__ bfp,
                          const float *__restrict__ Wi,
                          const float *__restrict__ bip,
                          const float *__restrict__ Wu,
                          const float *__restrict__ bup,
                          const float *__restrict__ Wo,
                          const float *__restrict__ bop, float4 (*red4)[NW],
                          float *by_l, const float *henc_s, float &h0,
                          float &h1, float &c0, float &c1) {
  // stage by[] to LDS (keeps it off the scalar-load path)
#pragma unroll
  for (int i = 0; i < (Tn * 4) / NTH; ++i)
    by_l[L.tid + i * NTH] = by[L.tid + i * NTH];
  __syncthreads();
  WB bufA = pf<DEC>(0, b, L.tid, x, Wy, Wf, bfp, Wi, bip, Wu, bup, Wo, bop);
  WB bufB;
  for (int t = 0; t < Tn; t += 2) {
    step<DEC, 0>(t, t + 1, bufA, bufB, b, L, x, Wy, Wf, bfp, Wi, bip, Wu, bup,
                 Wo, bop, red4, by_l, henc_s, h0, h1, c0, c1);
    step<DEC, 1>(t + 1, (t + 2 < Tn) ? (t + 2) : (Tn - 1), bufB, bufA, b, L, x,
                 Wy, Wf, bfp, Wi, bip, Wu, bup, Wo, bop, red4, by_l, henc_s,
                 h0, h1, c0, c1);
  }
}

__global__ __launch_bounds__(NTH, 2) void qlstm_ae_kernel(QParams p) {
  const int b = blockIdx.x;
  LaneCtx L;
  L.tid = threadIdx.x;
  L.lane = L.tid & 63;
  L.wid = L.tid >> 6;
  const int q = L.lane & 3, g = (L.lane >> 2) & 3;
  L.q1 = q & 1;
  L.q2 = q & 2;
  {
    const float *qwp = (g == 0) ? p.qw0 : (g == 1) ? p.qw1 : (g == 2) ? p.qw2 : p.qw3;
    L.w4lane = qwp[q];
  }
  L.mlane = (g == 2) ? 2.f : 1.f;
  L.alane = 1.f - L.mlane;
  L.klane = -L.mlane * 1.4426950408889634f;

  __shared__ float4 red4[2][NW];
  __shared__ float by_l[Tn * 4];
  __shared__ float henc_s[Hn];
  __shared__ float hst[Hn];

  float h0 = 0.f, h1 = 0.f, c0 = 0.f, c1 = 0.f;

  lstm_pass<false>(b, L, p.x, p.Wy_e, p.by_e, p.Wf_e, p.bf_e, p.Wi_e, p.bi_e,
                   p.Wu_e, p.bu_e, p.Wo_e, p.bo_e, red4, by_l, henc_s, h0, h1,
                   c0, c1);

  // stage h_enc for decoder input; reset state
  henc_s[L.tid] = h0;
  henc_s[L.tid + NTH] = h1;
  h0 = h1 = c0 = c1 = 0.f;
  __syncthreads();

  lstm_pass<true>(b, L, nullptr, p.Wy_d, p.by_d, p.Wf_d, p.bf_d, p.Wi_d,
                  p.bi_d, p.Wu_d, p.bu_d, p.Wo_d, p.bo_d, red4, by_l, henc_s,
                  h0, h1, c0, c1);

  // stage h_dec for the projection
  hst[L.tid] = h0;
  hst[L.tid + NTH] = h1;
  __syncthreads();

  // ---- target = h_dec @ Wt + bt ; out (B, T, 1); Wt is [H][T]
  {
    float acc = p.bt[L.tid];
    const float4 *h4 = (const float4 *)hst;
#pragma unroll 4
    for (int j4 = 0; j4 < Hn / 4; ++j4) {
      const float4 hv = h4[j4];
      acc = fmaf(hv.x, p.Wt[(j4 * 4 + 0) * Tn + L.tid], acc);
      acc = fmaf(hv.y, p.Wt[(j4 * 4 + 1) * Tn + L.tid], acc);
      acc = fmaf(hv.z, p.Wt[(j4 * 4 + 2) * Tn + L.tid], acc);
      acc = fmaf(hv.w, p.Wt[(j4 * 4 + 3) * Tn + L.tid], acc);
    }
    p.out[b * Tn + L.tid] = acc;
  }
}

extern "C" void kernel_launch(void *const *d_in, const int *in_sizes, int n_in,
                              void *d_out, int out_size, void *d_ws,
                              size_t ws_size, hipStream_t stream) {
  QParams p;
  p.x = (const float *)d_in[0];
  p.qw0 = (const float *)d_in[1];
  p.qw1 = (const float *)d_in[2];
  p.qw2 = (const float *)d_in[3];
  p.qw3 = (const float *)d_in[4];
  p.Wy_e = (const float *)d_in[5];
  p.by_e = (const float *)d_in[6];
  p.Wf_e = (const float *)d_in[7];
  p.bf_e = (const float *)d_in[8];
  p.Wi_e = (const float *)d_in[9];
  p.bi_e = (const float *)d_in[10];
  p.Wu_e = (const float *)d_in[11];
  p.bu_e = (const float *)d_in[12];
  p.Wo_e = (const float *)d_in[13];
  p.bo_e = (const float *)d_in[14];
  p.Wy_d = (const float *)d_in[15];
  p.by_d = (const float *)d_in[16];
  p.Wf_d = (const float *)d_in[17];
  p.bf_d = (const float *)d_in[18];
  p.Wi_d = (const float *)d_in[19];
  p.bi_d = (const float *)d_in[20];
  p.Wu_d = (const float *)d_in[21];
  p.bu_d = (const float *)d_in[22];
  p.Wo_d = (const float *)d_in[23];
  p.bo_d = (const float *)d_in[24];
  p.Wt = (const float *)d_in[25];
  p.bt = (const float *)d_in[26];
  p.out = (float *)d_out;

  hipLaunchKernelGGL(qlstm_ae_kernel, dim3(16), dim3(NTH), 0, stream, p);
}

// Round 4
// 909.572 us; speedup vs baseline: 3.0149x; 1.4680x over previous
//
#include <hip/hip_runtime.h>

#define Tn 512
#define Hn 1024
#define Fn 64
#define NTH 512
#define NW (NTH / 64)

#define REC_PASS (512ull * 512ull * 96ull) /* 24 MiB per pass */
#define YXE_OFF (2ull * REC_PASS)
#define WS_NEED (2ull * REC_PASS + 16ull * 512ull * 16ull)

typedef unsigned u32x4 __attribute__((ext_vector_type(4)));
typedef _Float16 half2v __attribute__((ext_vector_type(2)));

struct QParams {
  const float *x;
  const float *qw0, *qw1, *qw2, *qw3;
  const float *Wy_e, *by_e, *Wf_e, *bf_e, *Wi_e, *bi_e, *Wu_e, *bu_e, *Wo_e, *bo_e;
  const float *Wy_d, *by_d, *Wf_d, *bf_d, *Wi_d, *bi_d, *Wu_d, *bu_d, *Wo_d, *bo_d;
  const float *Wt, *bt;
  float *out;
};

// ---- sync / wait primitives -------------------------------------------------
// Raw barrier: drain LDS ops only; global loads stay in flight across it.
#define BAR()                                                                  \
  do {                                                                         \
    asm volatile("s_waitcnt lgkmcnt(0)" ::: "memory");                         \
    __builtin_amdgcn_s_barrier();                                              \
    asm volatile("" ::: "memory");                                             \
  } while (0)
// Counted vmem wait; sched_barrier stops hipcc hoisting register reads above
// the wait (rule #18).
#define WAIT_VM(N)                                                             \
  do {                                                                         \
    asm volatile("s_waitcnt vmcnt(" #N ")" ::: "memory");                      \
    __builtin_amdgcn_sched_barrier(0);                                         \
  } while (0)

// ---- DPP helpers ------------------------------------------------------------
template <int CTRL, int RM, int BM, bool BC>
__device__ __forceinline__ float dppadd(float x) {
  int t = __builtin_amdgcn_update_dpp(0, __builtin_bit_cast(int, x), CTRL, RM,
                                      BM, BC);
  return x + __builtin_bit_cast(float, t);
}
template <int CTRL>
__device__ __forceinline__ float dppmov(float x) {
  int t = __builtin_amdgcn_update_dpp(0, __builtin_bit_cast(int, x), CTRL, 0xF,
                                      0xF, true);
  return __builtin_bit_cast(float, t);
}
__device__ __forceinline__ float wave_sum63(float x) {
  x = dppadd<0xB1, 0xF, 0xF, true>(x);
  x = dppadd<0x4E, 0xF, 0xF, true>(x);
  x = dppadd<0x141, 0xF, 0xF, true>(x);
  x = dppadd<0x140, 0xF, 0xF, true>(x);
  x = dppadd<0x142, 0xA, 0xF, false>(x);
  x = dppadd<0x143, 0xC, 0xF, false>(x);
  return x; // lane 63 = wave total
}
__device__ __forceinline__ float sum8_all(float x) {
  x = dppadd<0xB1, 0xF, 0xF, true>(x);
  x = dppadd<0x4E, 0xF, 0xF, true>(x);
  x = dppadd<0x141, 0xF, 0xF, true>(x);
  return x;
}
__device__ __forceinline__ float tanhc(float c) {
  float e = __builtin_amdgcn_exp2f(c * 2.885390081777927f);
  return fmaf(-2.f, __builtin_amdgcn_rcpf(e + 1.f), 1.f);
}
__device__ __forceinline__ float2 cvt2(unsigned u) {
  half2v h = __builtin_bit_cast(half2v, u);
  return make_float2((float)h.x, (float)h.y);
}
__device__ __forceinline__ unsigned pkh(float a, float b) {
  half2v h;
  h.x = (_Float16)a;
  h.y = (_Float16)b;
  return __builtin_bit_cast(unsigned, h);
}

struct LaneCtx {
  int tid, lane, wid;
  bool q1, q2;
  float w4lane;
  float mlane, alane, klane;
};

// =============================================================================
// Pre-pass: convert weights to f16 records in d_ws.
// Record (t, j<512), 96 B:
//   [ 0..63]  gw: halves [e(2)][g(4)][n(4)] for jj = j + e*512
//   [64..79]  gb: halves [e][g]
//   [80..95]  wy: halves [e][q]  (Wy[t][jj][q])
// Encoder also emits yx[b][t][4] f32 = x(b,t,:)@Wy_e[t,1024:,:] + by_e[t].
// =============================================================================
__global__ __launch_bounds__(512) void qprep_kernel(QParams p, char *ws) {
  int t = blockIdx.x;
  const bool dec = (t >= 512);
  if (dec) t -= 512;
  const int j = threadIdx.x;

  const float *Wf = dec ? p.Wf_d : p.Wf_e, *Wi = dec ? p.Wi_d : p.Wi_e;
  const float *Wu = dec ? p.Wu_d : p.Wu_e, *Wo = dec ? p.Wo_d : p.Wo_e;
  const float *bf = dec ? p.bf_d : p.bf_e, *bi = dec ? p.bi_d : p.bi_e;
  const float *bu = dec ? p.bu_d : p.bu_e, *bo = dec ? p.bo_d : p.bo_e;
  const float *Wy = dec ? p.Wy_d : p.Wy_e;
  const int K = dec ? (Hn + 1) : (Hn + Fn);

  float wv[2][4][4], bv[2][4], wyv[2][4];
#pragma unroll
  for (int e = 0; e < 2; ++e) {
    const int jj = j + e * 512;
#pragma unroll
    for (int n = 0; n < 4; ++n) {
      const int gi = t * 4096 + n * 1024 + jj;
      wv[e][0][n] = Wf[gi];
      wv[e][1][n] = Wi[gi];
      wv[e][2][n] = Wu[gi];
      wv[e][3][n] = Wo[gi];
    }
    const int bidx = t * 1024 + jj;
    bv[e][0] = bf[bidx];
    bv[e][1] = bi[bidx];
    bv[e][2] = bu[bidx];
    bv[e][3] = bo[bidx];
    const float4 wr = *(const float4 *)(Wy + ((size_t)t * K + jj) * 4);
    wyv[e][0] = wr.x;
    wyv[e][1] = wr.y;
    wyv[e][2] = wr.z;
    wyv[e][3] = wr.w;
  }
  char *rec = ws + (dec ? REC_PASS : 0) + ((size_t)t * 512 + j) * 96;
  u32x4 s0 = {pkh(wv[0][0][0], wv[0][0][1]), pkh(wv[0][0][2], wv[0][0][3]),
              pkh(wv[0][1][0], wv[0][1][1]), pkh(wv[0][1][2], wv[0][1][3])};
  u32x4 s1 = {pkh(wv[0][2][0], wv[0][2][1]), pkh(wv[0][2][2], wv[0][2][3]),
              pkh(wv[0][3][0], wv[0][3][1]), pkh(wv[0][3][2], wv[0][3][3])};
  u32x4 s2 = {pkh(wv[1][0][0], wv[1][0][1]), pkh(wv[1][0][2], wv[1][0][3]),
              pkh(wv[1][1][0], wv[1][1][1]), pkh(wv[1][1][2], wv[1][1][3])};
  u32x4 s3 = {pkh(wv[1][2][0], wv[1][2][1]), pkh(wv[1][2][2], wv[1][2][3]),
              pkh(wv[1][3][0], wv[1][3][1]), pkh(wv[1][3][2], wv[1][3][3])};
  u32x4 s4 = {pkh(bv[0][0], bv[0][1]), pkh(bv[0][2], bv[0][3]),
              pkh(bv[1][0], bv[1][1]), pkh(bv[1][2], bv[1][3])};
  u32x4 s5 = {pkh(wyv[0][0], wyv[0][1]), pkh(wyv[0][2], wyv[0][3]),
              pkh(wyv[1][0], wyv[1][1]), pkh(wyv[1][2], wyv[1][3])};
  *(u32x4 *)(rec + 0) = s0;
  *(u32x4 *)(rec + 16) = s1;
  *(u32x4 *)(rec + 32) = s2;
  *(u32x4 *)(rec + 48) = s3;
  *(u32x4 *)(rec + 64) = s4;
  *(u32x4 *)(rec + 80) = s5;

  if (!dec && j < 16) { // yx[b][t] = x(b,t,:)@Wy_e[t,1024:,:] + by_e[t]
    const int b = j;
    float a0 = p.by_e[t * 4 + 0], a1 = p.by_e[t * 4 + 1],
          a2 = p.by_e[t * 4 + 2], a3 = p.by_e[t * 4 + 3];
#pragma unroll 8
    for (int k = 0; k < 64; ++k) {
      const float xv = p.x[((size_t)b * Tn + t) * Fn + k];
      const float4 wr =
          *(const float4 *)(p.Wy_e + ((size_t)t * (Hn + Fn) + Hn + k) * 4);
      a0 = fmaf(xv, wr.x, a0);
      a1 = fmaf(xv, wr.y, a1);
      a2 = fmaf(xv, wr.z, a2);
      a3 = fmaf(xv, wr.w, a3);
    }
    ((float4 *)(ws + YXE_OFF))[(size_t)b * Tn + t] =
        make_float4(a0, a1, a2, a3);
  }
}

// =============================================================================
// Main f16 scan kernel
// =============================================================================
struct Regs {
  u32x4 wy, g0, g1, g2, g3, gb;
};

__device__ __forceinline__ void issue_pf(Regs &r, const char *rec) {
  const unsigned long long a = (unsigned long long)rec;
  asm volatile("global_load_dwordx4 %0, %1, off offset:80" : "=v"(r.wy) : "v"(a));
  asm volatile("global_load_dwordx4 %0, %1, off offset:0" : "=v"(r.g0) : "v"(a));
  asm volatile("global_load_dwordx4 %0, %1, off offset:16" : "=v"(r.g1) : "v"(a));
  asm volatile("global_load_dwordx4 %0, %1, off offset:32" : "=v"(r.g2) : "v"(a));
  asm volatile("global_load_dwordx4 %0, %1, off offset:48" : "=v"(r.g3) : "v"(a));
  asm volatile("global_load_dwordx4 %0, %1, off offset:64" : "=v"(r.gb) : "v"(a));
}

__device__ __forceinline__ void qstep(int t, int tn, int par, const Regs &rd,
                                      Regs &wr, const char *recbase,
                                      const LaneCtx &L, float4 (*red4)[NW],
                                      const float *yxby_l, float &h0, float &h1,
                                      float &c0, float &c1) {
  WAIT_VM(5); // this step's wy (oldest outstanding load) has landed
  // ---------- phase A: y partials from registers, DPP reduce
  const float2 w00 = cvt2(rd.wy.x), w01 = cvt2(rd.wy.y);
  const float2 w10 = cvt2(rd.wy.z), w11 = cvt2(rd.wy.w);
  float a0 = h0 * w00.x, a1 = h0 * w00.y, a2 = h0 * w01.x, a3 = h0 * w01.y;
  a0 = fmaf(h1, w10.x, a0);
  a1 = fmaf(h1, w10.y, a1);
  a2 = fmaf(h1, w11.x, a2);
  a3 = fmaf(h1, w11.y, a3);
  const float yxs = yxby_l[t * 4 + (L.lane & 3)]; // drained at BAR
  a0 = wave_sum63(a0);
  a1 = wave_sum63(a1);
  a2 = wave_sum63(a2);
  a3 = wave_sum63(a3);
  if (L.lane == 63) red4[par][L.wid] = make_float4(a0, a1, a2, a3);
  // issue NEXT step's 6 loads; they stay in flight across the barrier
  issue_pf(wr, recbase + ((size_t)tn * 512 + L.tid) * 96);
  BAR();
  // ---------- phase B: finalize y, closed-form circuit, activations
  const float4 rv = red4[par][L.lane & 7];
  const float y0 = sum8_all(rv.x), y1 = sum8_all(rv.y), y2 = sum8_all(rv.z),
              y3 = sum8_all(rv.w);
  const float yq = L.q2 ? (L.q1 ? y3 : y2) : (L.q1 ? y1 : y0);
  const float ang = yq + yxs + L.w4lane;
  const float cc = __cosf(ang);
  const float t1 = dppmov<0xB1>(cc);
  const float d1 = cc * t1;
  const float t2 = dppmov<0x4E>(d1);
  const float d2 = d1 * t2;
  const float zu = t1 * t2;
  const float zv = cc * t2;
  const float z = L.q2 ? (L.q1 ? d2 : zv) : (L.q1 ? d1 : zu);
  const float s =
      __builtin_amdgcn_rcpf(1.f + __builtin_amdgcn_exp2f(L.klane * z));
  const float act = fmaf(s, L.mlane, L.alane);
#define RL(n)                                                                  \
  __builtin_bit_cast(float,                                                    \
                     __builtin_amdgcn_readlane(__builtin_bit_cast(int, act), n))
  const float F0 = RL(0), F1 = RL(1), F2 = RL(2), F3 = RL(3);
  const float I0 = RL(4), I1 = RL(5), I2 = RL(6), I3 = RL(7);
  const float U0 = RL(8), U1 = RL(9), U2 = RL(10), U3 = RL(11);
  const float O0 = RL(12), O1 = RL(13), O2 = RL(14), O3 = RL(15);
#undef RL
  WAIT_VM(6); // this step's gates/biases landed; next step's 6 still flying
  // ---------- phase C: gate matvecs + state update (outputs tid, tid+512)
  {
    const float2 f01 = cvt2(rd.g0.x), f23 = cvt2(rd.g0.y);
    const float2 i01 = cvt2(rd.g0.z), i23 = cvt2(rd.g0.w);
    const float2 u01 = cvt2(rd.g1.x), u23 = cvt2(rd.g1.y);
    const float2 o01 = cvt2(rd.g1.z), o23 = cvt2(rd.g1.w);
    const float2 bfi = cvt2(rd.gb.x), buo = cvt2(rd.gb.y);
    float fv = fmaf(F0, f01.x, bfi.x);
    fv = fmaf(F1, f01.y, fv);
    fv = fmaf(F2, f23.x, fv);
    fv = fmaf(F3, f23.y, fv);
    float iv = fmaf(I0, i01.x, bfi.y);
    iv = fmaf(I1, i01.y, iv);
    iv = fmaf(I2, i23.x, iv);
    iv = fmaf(I3, i23.y, iv);
    float uv = fmaf(U0, u01.x, buo.x);
    uv = fmaf(U1, u01.y, uv);
    uv = fmaf(U2, u23.x, uv);
    uv = fmaf(U3, u23.y, uv);
    float ov = fmaf(O0, o01.x, buo.y);
    ov = fmaf(O1, o01.y, ov);
    ov = fmaf(O2, o23.x, ov);
    ov = fmaf(O3, o23.y, ov);
    c0 = fmaf(fv, c0, iv * uv);
    h0 = ov * tanhc(c0);
  }
  {
    const float2 f01 = cvt2(rd.g2.x), f23 = cvt2(rd.g2.y);
    const float2 i01 = cvt2(rd.g2.z), i23 = cvt2(rd.g2.w);
    const float2 u01 = cvt2(rd.g3.x), u23 = cvt2(rd.g3.y);
    const float2 o01 = cvt2(rd.g3.z), o23 = cvt2(rd.g3.w);
    const float2 bfi = cvt2(rd.gb.z), buo = cvt2(rd.gb.w);
    float fv = fmaf(F0, f01.x, bfi.x);
    fv = fmaf(F1, f01.y, fv);
    fv = fmaf(F2, f23.x, fv);
    fv = fmaf(F3, f23.y, fv);
    float iv = fmaf(I0, i01.x, bfi.y);
    iv = fmaf(I1, i01.y, iv);
    iv = fmaf(I2, i23.x, iv);
    iv = fmaf(I3, i23.y, iv);
    float uv = fmaf(U0, u01.x, buo.x);
    uv = fmaf(U1, u01.y, uv);
    uv = fmaf(U2, u23.x, uv);
    uv = fmaf(U3, u23.y, uv);
    float ov = fmaf(O0, o01.x, buo.y);
    ov = fmaf(O1, o01.y, ov);
    ov = fmaf(O2, o23.x, ov);
    ov = fmaf(O3, o23.y, ov);
    c1 = fmaf(fv, c1, iv * uv);
    h1 = ov * tanhc(c1);
  }
}

__global__ __launch_bounds__(NTH, 2) void qlstm_f16_kernel(QParams p,
                                                           const char *ws) {
  const int b = blockIdx.x;
  LaneCtx L;
  L.tid = threadIdx.x;
  L.lane = L.tid & 63;
  L.wid = L.tid >> 6;
  const int q = L.lane & 3, g = (L.lane >> 2) & 3;
  L.q1 = q & 1;
  L.q2 = q & 2;
  {
    const float *qwp =
        (g == 0) ? p.qw0 : (g == 1) ? p.qw1 : (g == 2) ? p.qw2 : p.qw3;
    L.w4lane = qwp[q];
  }
  L.mlane = (g == 2) ? 2.f : 1.f;
  L.alane = 1.f - L.mlane;
  L.klane = -L.mlane * 1.4426950408889634f;

  __shared__ float4 red4[2][NW];
  __shared__ __align__(16) float yxby_l[Tn * 4];
  __shared__ __align__(16) float hbuf[Hn];

  const char *enc = ws;
  const char *dec = ws + REC_PASS;

  // ---- encoder prologue: stage yx(+by) table
  ((float4 *)yxby_l)[L.tid] =
      ((const float4 *)(ws + YXE_OFF))[(size_t)b * Tn + L.tid];
  float h0 = 0.f, h1 = 0.f, c0 = 0.f, c1 = 0.f;
  __syncthreads();

  Regs A, B;
  WAIT_VM(0);
  issue_pf(A, enc + (size_t)L.tid * 96);
  for (int t = 0; t < Tn; t += 2) {
    qstep(t, t + 1, 0, A, B, enc, L, red4, yxby_l, h0, h1, c0, c1);
    qstep(t + 1, (t + 2 < Tn) ? (t + 2) : (Tn - 1), 1, B, A, enc, L, red4,
          yxby_l, h0, h1, c0, c1);
  }
  WAIT_VM(0);

  // ---- transition: stage h_enc, build decoder yx table
  hbuf[L.tid] = h0;
  hbuf[L.tid + NTH] = h1;
  __syncthreads();
  {
    const float hv = hbuf[L.tid]; // = h_enc[t] for t = tid
    const float4 wx =
        *(const float4 *)(p.Wy_d + ((size_t)L.tid * (Hn + 1) + Hn) * 4);
    const float4 bd = *(const float4 *)(p.by_d + L.tid * 4);
    ((float4 *)yxby_l)[L.tid] =
        make_float4(fmaf(hv, wx.x, bd.x), fmaf(hv, wx.y, bd.y),
                    fmaf(hv, wx.z, bd.z), fmaf(hv, wx.w, bd.w));
  }
  h0 = h1 = c0 = c1 = 0.f;
  __syncthreads();

  WAIT_VM(0);
  issue_pf(A, dec + (size_t)L.tid * 96);
  for (int t = 0; t < Tn; t += 2) {
    qstep(t, t + 1, 0, A, B, dec, L, red4, yxby_l, h0, h1, c0, c1);
    qstep(t + 1, (t + 2 < Tn) ? (t + 2) : (Tn - 1), 1, B, A, dec, L, red4,
          yxby_l, h0, h1, c0, c1);
  }
  WAIT_VM(0);

  // ---- projection: out[b][t] = h_dec @ Wt[:,t] + bt[t]
  hbuf[L.tid] = h0;
  hbuf[L.tid + NTH] = h1;
  __syncthreads();
  {
    float acc = p.bt[L.tid];
    const float4 *h4 = (const float4 *)hbuf;
#pragma unroll 4
    for (int j4 = 0; j4 < Hn / 4; ++j4) {
      const float4 hv = h4[j4];
      acc = fmaf(hv.x, p.Wt[(j4 * 4 + 0) * Tn + L.tid], acc);
      acc = fmaf(hv.y, p.Wt[(j4 * 4 + 1) * Tn + L.tid], acc);
      acc = fmaf(hv.z, p.Wt[(j4 * 4 + 2) * Tn + L.tid], acc);
      acc = fmaf(hv.w, p.Wt[(j4 * 4 + 3) * Tn + L.tid], acc);
    }
    p.out[(size_t)b * Tn + L.tid] = acc;
  }
}

// =============================================================================
// Fallback (round-3 kernel, f32 direct): used if ws_size < WS_NEED.
// =============================================================================
struct WB {
  float w[32];
  float bb[8];
  float4 wy0, wy1;
  float4 wyx;
  float xv;
};

template <bool DEC>
__device__ __forceinline__ WB
pf_fb(int t, int b, int tid, const float *__restrict__ x,
      const float *__restrict__ Wy, const float *__restrict__ Wf,
      const float *__restrict__ bfp, const float *__restrict__ Wi,
      const float *__restrict__ bip, const float *__restrict__ Wu,
      const float *__restrict__ bup, const float *__restrict__ Wo,
      const float *__restrict__ bop) {
  WB d;
  const int K = DEC ? (Hn + 1) : (Hn + Fn);
  const int g0 = t * 4096 + tid;
#pragma unroll
  for (int e = 0; e < 2; ++e) {
    const int ge = g0 + e * 512;
#pragma unroll
    for (int n = 0; n < 4; ++n) {
      d.w[e * 16 + 0 * 4 + n] = Wf[ge + n * 1024];
      d.w[e * 16 + 1 * 4 + n] = Wi[ge + n * 1024];
      d.w[e * 16 + 2 * 4 + n] = Wu[ge + n * 1024];
      d.w[e * 16 + 3 * 4 + n] = Wo[ge + n * 1024];
    }
    const int be = t * 1024 + tid + e * 512;
    d.bb[e * 4 + 0] = bfp[be];
    d.bb[e * 4 + 1] = bip[be];
    d.bb[e * 4 + 2] = bup[be];
    d.bb[e * 4 + 3] = bop[be];
  }
  d.wy0 = *(const float4 *)(Wy + (t * K + tid) * 4);
  d.wy1 = *(const float4 *)(Wy + (t * K + tid + 512) * 4);
  if (!DEC) {
    if (tid < Fn) {
      d.wyx = *(const float4 *)(Wy + (t * K + Hn + tid) * 4);
      d.xv = x[(b * Tn + t) * Fn + tid];
    }
  } else {
    if (tid == 0) d.wyx = *(const float4 *)(Wy + (t * K + Hn) * 4);
  }
  return d;
}

template <bool DEC, int PAR>
__device__ __forceinline__ void
step_fb(int t, int tn, const WB &rd, WB &wr, int b, const LaneCtx &L,
        const float *__restrict__ x, const float *__restrict__ Wy,
        const float *__restrict__ Wf, const float *__restrict__ bfp,
        const float *__restrict__ Wi, const float *__restrict__ bip,
        const float *__restrict__ Wu, const float *__restrict__ bup,
        const float *__restrict__ Wo, const float *__restrict__ bop,
        float4 (*red4)[NW], const float *by_l, const float *henc_s, float &h0,
        float &h1, float &c0, float &c1) {
  float a0 = h0 * rd.wy0.x, a1 = h0 * rd.wy0.y, a2 = h0 * rd.wy0.z,
        a3 = h0 * rd.wy0.w;
  a0 = fmaf(h1, rd.wy1.x, a0);
  a1 = fmaf(h1, rd.wy1.y, a1);
  a2 = fmaf(h1, rd.wy1.z, a2);
  a3 = fmaf(h1, rd.wy1.w, a3);
  if (!DEC) {
    if (L.tid < Fn) {
      a0 = fmaf(rd.xv, rd.wyx.x, a0);
      a1 = fmaf(rd.xv, rd.wyx.y, a1);
      a2 = fmaf(rd.xv, rd.wyx.z, a2);
      a3 = fmaf(rd.xv, rd.wyx.w, a3);
    }
  } else {
    if (L.tid == 0) {
      const float xv = henc_s[t];
      a0 = fmaf(xv, rd.wyx.x, a0);
      a1 = fmaf(xv, rd.wyx.y, a1);
      a2 = fmaf(xv, rd.wyx.z, a2);
      a3 = fmaf(xv, rd.wyx.w, a3);
    }
  }
  a0 = wave_sum63(a0);
  a1 = wave_sum63(a1);
  a2 = wave_sum63(a2);
  a3 = wave_sum63(a3);
  if (L.lane == 63) red4[PAR][L.wid] = make_float4(a0, a1, a2, a3);
  wr = pf_fb<DEC>(tn, b, L.tid, x, Wy, Wf, bfp, Wi, bip, Wu, bup, Wo, bop);
  BAR();
  float4 rv = red4[PAR][L.lane & 7];
  const float byq = by_l[t * 4 + (L.lane & 3)];
  float y0 = sum8_all(rv.x), y1 = sum8_all(rv.y), y2 = sum8_all(rv.z),
        y3 = sum8_all(rv.w);
  const float yq = L.q2 ? (L.q1 ? y3 : y2) : (L.q1 ? y1 : y0);
  const float ang = yq + byq + L.w4lane;
  const float cc = __cosf(ang);
  const float t1 = dppmov<0xB1>(cc);
  const float d1 = cc * t1;
  const float t2 = dppmov<0x4E>(d1);
  const float d2 = d1 * t2;
  const float zu = t1 * t2;
  const float zv = cc * t2;
  const float z = L.q2 ? (L.q1 ? d2 : zv) : (L.q1 ? d1 : zu);
  const float s =
      __builtin_amdgcn_rcpf(1.f + __builtin_amdgcn_exp2f(L.klane * z));
  const float act = fmaf(s, L.mlane, L.alane);
#define RL(n)                                                                  \
  __builtin_bit_cast(float,                                                    \
                     __builtin_amdgcn_readlane(__builtin_bit_cast(int, act), n))
  const float f0 = RL(0), f1 = RL(1), f2 = RL(2), f3 = RL(3);
  const float i0 = RL(4), i1 = RL(5), i2 = RL(6), i3 = RL(7);
  const float u0 = RL(8), u1 = RL(9), u2 = RL(10), u3 = RL(11);
  const float o0 = RL(12), o1 = RL(13), o2 = RL(14), o3 = RL(15);
#undef RL
#pragma unroll
  for (int e = 0; e < 2; ++e) {
    float fv = rd.bb[e * 4 + 0], iv = rd.bb[e * 4 + 1], uv = rd.bb[e * 4 + 2],
          ov = rd.bb[e * 4 + 3];
    fv = fmaf(f0, rd.w[e * 16 + 0], fv);
    fv = fmaf(f1, rd.w[e * 16 + 1], fv);
    fv = fmaf(f2, rd.w[e * 16 + 2], fv);
    fv = fmaf(f3, rd.w[e * 16 + 3], fv);
    iv = fmaf(i0, rd.w[e * 16 + 4], iv);
    iv = fmaf(i1, rd.w[e * 16 + 5], iv);
    iv = fmaf(i2, rd.w[e * 16 + 6], iv);
    iv = fmaf(i3, rd.w[e * 16 + 7], iv);
    uv = fmaf(u0, rd.w[e * 16 + 8], uv);
    uv = fmaf(u1, rd.w[e * 16 + 9], uv);
    uv = fmaf(u2, rd.w[e * 16 + 10], uv);
    uv = fmaf(u3, rd.w[e * 16 + 11], uv);
    ov = fmaf(o0, rd.w[e * 16 + 12], ov);
    ov = fmaf(o1, rd.w[e * 16 + 13], ov);
    ov = fmaf(o2, rd.w[e * 16 + 14], ov);
    ov = fmaf(o3, rd.w[e * 16 + 15], ov);
    float &cr = e ? c1 : c0;
    float &hr = e ? h1 : h0;
    const float cn = fmaf(fv, cr, iv * uv);
    cr = cn;
    hr = ov * tanhc(cn);
  }
}

template <bool DEC>
__device__ void lstm_pass_fb(int b, const LaneCtx &L,
                             const float *__restrict__ x,
                             const float *__restrict__ Wy,
                             const float *__restrict__ by,
                             const float *__restrict__ Wf,
                             const float *__restrict__ bfp,
                             const float *__restrict__ Wi,
                             const float *__restrict__ bip,
                             const float *__restrict__ Wu,
                             const float *__restrict__ bup,
                             const float *__restrict__ Wo,
                             const float *__restrict__ bop,
                             float4 (*red4)[NW], float *by_l,
                             const float *henc_s, float &h0, float &h1,
                             float &c0, float &c1) {
#pragma unroll
  for (int i = 0; i < (Tn * 4) / NTH; ++i)
    by_l[L.tid + i * NTH] = by[L.tid + i * NTH];
  __syncthreads();
  WB bufA = pf_fb<DEC>(0, b, L.tid, x, Wy, Wf, bfp, Wi, bip, Wu, bup, Wo, bop);
  WB bufB;
  for (int t = 0; t < Tn; t += 2) {
    step_fb<DEC, 0>(t, t + 1, bufA, bufB, b, L, x, Wy, Wf, bfp, Wi, bip, Wu,
                    bup, Wo, bop, red4, by_l, henc_s, h0, h1, c0, c1);
    step_fb<DEC, 1>(t + 1, (t + 2 < Tn) ? (t + 2) : (Tn - 1), bufB, bufA, b, L,
                    x, Wy, Wf, bfp, Wi, bip, Wu, bup, Wo, bop, red4, by_l,
                    henc_s, h0, h1, c0, c1);
  }
}

__global__ __launch_bounds__(NTH, 2) void qlstm_fb_kernel(QParams p) {
  const int b = blockIdx.x;
  LaneCtx L;
  L.tid = threadIdx.x;
  L.lane = L.tid & 63;
  L.wid = L.tid >> 6;
  const int q = L.lane & 3, g = (L.lane >> 2) & 3;
  L.q1 = q & 1;
  L.q2 = q & 2;
  {
    const float *qwp =
        (g == 0) ? p.qw0 : (g == 1) ? p.qw1 : (g == 2) ? p.qw2 : p.qw3;
    L.w4lane = qwp[q];
  }
  L.mlane = (g == 2) ? 2.f : 1.f;
  L.alane = 1.f - L.mlane;
  L.klane = -L.mlane * 1.4426950408889634f;

  __shared__ float4 red4[2][NW];
  __shared__ float by_l[Tn * 4];
  __shared__ float henc_s[Hn];
  __shared__ float hst[Hn];

  float h0 = 0.f, h1 = 0.f, c0 = 0.f, c1 = 0.f;

  lstm_pass_fb<false>(b, L, p.x, p.Wy_e, p.by_e, p.Wf_e, p.bf_e, p.Wi_e,
                      p.bi_e, p.Wu_e, p.bu_e, p.Wo_e, p.bo_e, red4, by_l,
                      henc_s, h0, h1, c0, c1);
  henc_s[L.tid] = h0;
  henc_s[L.tid + NTH] = h1;
  h0 = h1 = c0 = c1 = 0.f;
  __syncthreads();
  lstm_pass_fb<true>(b, L, nullptr, p.Wy_d, p.by_d, p.Wf_d, p.bf_d, p.Wi_d,
                     p.bi_d, p.Wu_d, p.bu_d, p.Wo_d, p.bo_d, red4, by_l,
                     henc_s, h0, h1, c0, c1);
  hst[L.tid] = h0;
  hst[L.tid + NTH] = h1;
  __syncthreads();
  {
    float acc = p.bt[L.tid];
    const float4 *h4 = (const float4 *)hst;
#pragma unroll 4
    for (int j4 = 0; j4 < Hn / 4; ++j4) {
      const float4 hv = h4[j4];
      acc = fmaf(hv.x, p.Wt[(j4 * 4 + 0) * Tn + L.tid], acc);
      acc = fmaf(hv.y, p.Wt[(j4 * 4 + 1) * Tn + L.tid], acc);
      acc = fmaf(hv.z, p.Wt[(j4 * 4 + 2) * Tn + L.tid], acc);
      acc = fmaf(hv.w, p.Wt[(j4 * 4 + 3) * Tn + L.tid], acc);
    }
    p.out[(size_t)b * Tn + L.tid] = acc;
  }
}

extern "C" void kernel_launch(void *const *d_in, const int *in_sizes, int n_in,
                              void *d_out, int out_size, void *d_ws,
                              size_t ws_size, hipStream_t stream) {
  QParams p;
  p.x = (const float *)d_in[0];
  p.qw0 = (const float *)d_in[1];
  p.qw1 = (const float *)d_in[2];
  p.qw2 = (const float *)d_in[3];
  p.qw3 = (const float *)d_in[4];
  p.Wy_e = (const float *)d_in[5];
  p.by_e = (const float *)d_in[6];
  p.Wf_e = (const float *)d_in[7];
  p.bf_e = (const float *)d_in[8];
  p.Wi_e = (const float *)d_in[9];
  p.bi_e = (const float *)d_in[10];
  p.Wu_e = (const float *)d_in[11];
  p.bu_e = (const float *)d_in[12];
  p.Wo_e = (const float *)d_in[13];
  p.bo_e = (const float *)d_in[14];
  p.Wy_d = (const float *)d_in[15];
  p.by_d = (const float *)d_in[16];
  p.Wf_d = (const float *)d_in[17];
  p.bf_d = (const float *)d_in[18];
  p.Wi_d = (const float *)d_in[19];
  p.bi_d = (const float *)d_in[20];
  p.Wu_d = (const float *)d_in[21];
  p.bu_d = (const float *)d_in[22];
  p.Wo_d = (const float *)d_in[23];
  p.bo_d = (const float *)d_in[24];
  p.Wt = (const float *)d_in[25];
  p.bt = (const float *)d_in[26];
  p.out = (float *)d_out;

  if (ws_size >= WS_NEED) {
    char *ws = (char *)d_ws;
    hipLaunchKernelGGL(qprep_kernel, dim3(1024), dim3(512), 0, stream, p, ws);
    hipLaunchKernelGGL(qlstm_f16_kernel, dim3(16), dim3(NTH), 0, stream, p, ws);
  } else {
    hipLaunchKernelGGL(qlstm_fb_kernel, dim3(16), dim3(NTH), 0, stream, p);
  }
}

// Round 6
// 740.596 us; speedup vs baseline: 3.7028x; 1.2282x over previous
//
#include <hip/hip_runtime.h>

#define Tn 512
#define Hn 1024
#define Fn 64
#define NTH 512
#define NW (NTH / 64)

#define STEPB (6u * 512u * 16u) /* 49152 B per timestep of records */
#define MAXTOFF (511u * STEPB)
#define REC_PASS ((unsigned long long)Tn * STEPB) /* 24 MiB per pass */
#define YXE_OFF (2ull * REC_PASS)
#define WS_NEED (2ull * REC_PASS + 16ull * 512ull * 16ull)

typedef unsigned u32x4 __attribute__((ext_vector_type(4)));
typedef __fp16 h2 __attribute__((ext_vector_type(2)));

struct QParams {
  const float *x;
  const float *qw0, *qw1, *qw2, *qw3;
  const float *Wy_e, *by_e, *Wf_e, *bf_e, *Wi_e, *bi_e, *Wu_e, *bu_e, *Wo_e, *bo_e;
  const float *Wy_d, *by_d, *Wf_d, *bf_d, *Wi_d, *bi_d, *Wu_d, *bu_d, *Wo_d, *bo_d;
  const float *Wt, *bt;
  float *out;
};

// ---- sync / wait primitives -------------------------------------------------
// Raw barrier: drain LDS ops only; global loads stay in flight across it.
#define BAR()                                                                  \
  do {                                                                         \
    asm volatile("s_waitcnt lgkmcnt(0)" ::: "memory");                         \
    __builtin_amdgcn_s_barrier();                                              \
    asm volatile("" ::: "memory");                                             \
  } while (0)
// Counted vmem wait; sched_barrier stops hipcc hoisting register reads above
// the wait (rule #18).
#define WAIT_VM(N)                                                             \
  do {                                                                         \
    asm volatile("s_waitcnt vmcnt(" #N ")" ::: "memory");                      \
    __builtin_amdgcn_sched_barrier(0);                                         \
  } while (0)

// ---- DPP / packed helpers ---------------------------------------------------
template <int CTRL, int RM, int BM, bool BC>
__device__ __forceinline__ float dppadd(float x) {
  int t = __builtin_amdgcn_update_dpp(0, __builtin_bit_cast(int, x), CTRL, RM,
                                      BM, BC);
  return x + __builtin_bit_cast(float, t);
}
template <int CTRL>
__device__ __forceinline__ float dppmov(float x) {
  int t = __builtin_amdgcn_update_dpp(0, __builtin_bit_cast(int, x), CTRL, 0xF,
                                      0xF, true);
  return __builtin_bit_cast(float, t);
}
__device__ __forceinline__ float wave_sum63(float x) {
  x = dppadd<0xB1, 0xF, 0xF, true>(x);
  x = dppadd<0x4E, 0xF, 0xF, true>(x);
  x = dppadd<0x141, 0xF, 0xF, true>(x);
  x = dppadd<0x140, 0xF, 0xF, true>(x);
  x = dppadd<0x142, 0xA, 0xF, false>(x);
  x = dppadd<0x143, 0xC, 0xF, false>(x);
  return x; // lane 63 = wave total
}
__device__ __forceinline__ float sum8_all(float x) {
  x = dppadd<0xB1, 0xF, 0xF, true>(x);
  x = dppadd<0x4E, 0xF, 0xF, true>(x);
  x = dppadd<0x141, 0xF, 0xF, true>(x);
  return x;
}
__device__ __forceinline__ float tanhc(float c) {
  float e = __builtin_amdgcn_exp2f(c * 2.885390081777927f);
  return fmaf(-2.f, __builtin_amdgcn_rcpf(e + 1.f), 1.f);
}
__device__ __forceinline__ h2 pk2(float a, float b) {
  return __builtin_amdgcn_cvt_pkrtz(a, b);
}
__device__ __forceinline__ h2 uh(unsigned u) { return __builtin_bit_cast(h2, u); }
__device__ __forceinline__ float fdot2f(h2 a, h2 b, float c) {
#if __has_builtin(__builtin_amdgcn_fdot2)
  return __builtin_amdgcn_fdot2(a, b, c, false);
#else
  float d;
  asm("v_dot2_f32_f16 %0, %1, %2, %3" : "=v"(d) : "v"(a), "v"(b), "v"(c));
  return d;
#endif
}
__device__ __forceinline__ unsigned pkh(float a, float b) { // RNE pack (prep)
  h2 h;
  h.x = (__fp16)a;
  h.y = (__fp16)b;
  return __builtin_bit_cast(unsigned, h);
}

struct LaneCtx {
  int tid, lane, wid;
  unsigned jt16;
  bool q1, q2;
  float w4lane;
  float mlane, alane, klane;
};
struct SBase {
  unsigned long long a[6];
};

// =============================================================================
// Pre-pass: f16 records, COMPONENT-MAJOR: ws[pass][t][comp(6)][j(512)] u32x4.
//   comp g in 0..3 (f,i,u,o): { h2(Wg[t][0][j],Wg[t][1][j]),
//                               h2(Wg[t][2][j],Wg[t][3][j]),
//                               h2(Wg[t][0][j+512],Wg[t][1][j+512]),
//                               h2(Wg[t][2][j+512],Wg[t][3][j+512]) }
//   comp 4: { h2(bf[j],bf[j+512]), h2(bi..), h2(bu..), h2(bo..) }
//   comp 5: { h2(Wy[j][q],Wy[j+512][q]) for q=0..3 }
// Encoder also emits yx[b][t][4] f32 = x(b,t,:)@Wy_e[t,1024:,:] + by_e[t].
// =============================================================================
__global__ __launch_bounds__(512) void qprep_kernel(QParams p, char *ws) {
  int t = blockIdx.x;
  const bool dec = (t >= 512);
  if (dec) t -= 512;
  const int j = threadIdx.x;

  const float *Wg0 = dec ? p.Wf_d : p.Wf_e, *Wg1 = dec ? p.Wi_d : p.Wi_e;
  const float *Wg2 = dec ? p.Wu_d : p.Wu_e, *Wg3 = dec ? p.Wo_d : p.Wo_e;
  const float *bf = dec ? p.bf_d : p.bf_e, *bi = dec ? p.bi_d : p.bi_e;
  const float *bu = dec ? p.bu_d : p.bu_e, *bo = dec ? p.bo_d : p.bo_e;
  const float *Wy = dec ? p.Wy_d : p.Wy_e;
  const int K = dec ? (Hn + 1) : (Hn + Fn);

  u32x4 *dst = (u32x4 *)(ws + (dec ? REC_PASS : 0));
  const int rbase = t * 6 * 512 + j;
  const int t4 = t * 4096;
  const float *Wg[4] = {Wg0, Wg1, Wg2, Wg3};
#pragma unroll
  for (int g = 0; g < 4; ++g) {
    u32x4 v;
    v.x = pkh(Wg[g][t4 + 0 * 1024 + j], Wg[g][t4 + 1 * 1024 + j]);
    v.y = pkh(Wg[g][t4 + 2 * 1024 + j], Wg[g][t4 + 3 * 1024 + j]);
    v.z = pkh(Wg[g][t4 + 0 * 1024 + j + 512], Wg[g][t4 + 1 * 1024 + j + 512]);
    v.w = pkh(Wg[g][t4 + 2 * 1024 + j + 512], Wg[g][t4 + 3 * 1024 + j + 512]);
    dst[rbase + g * 512] = v;
  }
  {
    const int tb = t * 1024;
    u32x4 v = {pkh(bf[tb + j], bf[tb + j + 512]),
               pkh(bi[tb + j], bi[tb + j + 512]),
               pkh(bu[tb + j], bu[tb + j + 512]),
               pkh(bo[tb + j], bo[tb + j + 512])};
    dst[rbase + 4 * 512] = v;
  }
  {
    const float4 w0 = *(const float4 *)(Wy + ((size_t)t * K + j) * 4);
    const float4 w1 = *(const float4 *)(Wy + ((size_t)t * K + j + 512) * 4);
    u32x4 v = {pkh(w0.x, w1.x), pkh(w0.y, w1.y), pkh(w0.z, w1.z),
               pkh(w0.w, w1.w)};
    dst[rbase + 5 * 512] = v;
  }

  if (!dec && j < 16) { // yx[b][t] = x(b,t,:)@Wy_e[t,1024:,:] + by_e[t]
    const int b = j;
    float a0 = p.by_e[t * 4 + 0], a1 = p.by_e[t * 4 + 1],
          a2 = p.by_e[t * 4 + 2], a3 = p.by_e[t * 4 + 3];
#pragma unroll 8
    for (int k = 0; k < 64; ++k) {
      const float xv = p.x[((size_t)b * Tn + t) * Fn + k];
      const float4 wr =
          *(const float4 *)(p.Wy_e + ((size_t)t * (Hn + Fn) + Hn + k) * 4);
      a0 = fmaf(xv, wr.x, a0);
      a1 = fmaf(xv, wr.y, a1);
      a2 = fmaf(xv, wr.z, a2);
      a3 = fmaf(xv, wr.w, a3);
    }
    ((float4 *)(ws + YXE_OFF))[(size_t)b * Tn + t] =
        make_float4(a0, a1, a2, a3);
  }
}

// =============================================================================
// Main f16 scan kernel: 4-deep pipelined, coalesced component loads, dot2 math
// =============================================================================
struct Regs {
  u32x4 c0, c1, c2, c3, c4, c5; // gates f,i,u,o | biases | wy
};

__device__ __forceinline__ void issue_pf(Regs &r, const SBase &sb,
                                         unsigned voff) {
  asm volatile("global_load_dwordx4 %0, %1, %2" : "=v"(r.c5) : "v"(voff), "s"(sb.a[5]));
  asm volatile("global_load_dwordx4 %0, %1, %2" : "=v"(r.c0) : "v"(voff), "s"(sb.a[0]));
  asm volatile("global_load_dwordx4 %0, %1, %2" : "=v"(r.c1) : "v"(voff), "s"(sb.a[1]));
  asm volatile("global_load_dwordx4 %0, %1, %2" : "=v"(r.c2) : "v"(voff), "s"(sb.a[2]));
  asm volatile("global_load_dwordx4 %0, %1, %2" : "=v"(r.c3) : "v"(voff), "s"(sb.a[3]));
  asm volatile("global_load_dwordx4 %0, %1, %2" : "=v"(r.c4) : "v"(voff), "s"(sb.a[4]));
}

template <int PAR>
__device__ __forceinline__ void
qstep(int t, Regs &r, unsigned &toff, const SBase &sb, const LaneCtx &L,
      float4 (*red4)[NW], const float *yxby_l, float &h0, float &h1, float &c0,
      float &c1, h2 &hp) {
  WAIT_VM(18); // this step's 6 loads landed; 18 (3 steps) still in flight
  // ---------- phase A: y partials via v_dot2_f32_f16, DPP wave reduce
  float a0 = fdot2f(hp, uh(r.c5.x), 0.f);
  float a1 = fdot2f(hp, uh(r.c5.y), 0.f);
  float a2 = fdot2f(hp, uh(r.c5.z), 0.f);
  float a3 = fdot2f(hp, uh(r.c5.w), 0.f);
  a0 = wave_sum63(a0);
  a1 = wave_sum63(a1);
  a2 = wave_sum63(a2);
  a3 = wave_sum63(a3);
  if (L.lane == 63) red4[PAR][L.wid] = make_float4(a0, a1, a2, a3);
  BAR();
  // ---------- phase B: finalize y, closed-form circuit, packed activations
  const float4 rv = red4[PAR][L.lane & 7];
  const float yxs = yxby_l[t * 4 + (L.lane & 3)];
  const float y0 = sum8_all(rv.x), y1 = sum8_all(rv.y), y2 = sum8_all(rv.z),
              y3 = sum8_all(rv.w);
  const float yq = L.q2 ? (L.q1 ? y3 : y2) : (L.q1 ? y1 : y0);
  const float ang = yq + yxs + L.w4lane;
  const float cc = __cosf(ang);
  const float t1 = dppmov<0xB1>(cc);
  const float d1 = cc * t1;
  const float t2 = dppmov<0x4E>(d1);
  const float d2 = d1 * t2;
  const float zu = t1 * t2;
  const float zv = cc * t2;
  const float z = L.q2 ? (L.q1 ? d2 : zv) : (L.q1 ? d1 : zu);
  const float s =
      __builtin_amdgcn_rcpf(1.f + __builtin_amdgcn_exp2f(L.klane * z));
  const float act = fmaf(s, L.mlane, L.alane);
  const float actn = dppmov<0xB1>(act);
  const unsigned apk = __builtin_bit_cast(unsigned, pk2(act, actn));
  const h2 F01 = uh((unsigned)__builtin_amdgcn_readlane(apk, 0));
  const h2 F23 = uh((unsigned)__builtin_amdgcn_readlane(apk, 2));
  const h2 I01 = uh((unsigned)__builtin_amdgcn_readlane(apk, 4));
  const h2 I23 = uh((unsigned)__builtin_amdgcn_readlane(apk, 6));
  const h2 U01 = uh((unsigned)__builtin_amdgcn_readlane(apk, 8));
  const h2 U23 = uh((unsigned)__builtin_amdgcn_readlane(apk, 10));
  const h2 O01 = uh((unsigned)__builtin_amdgcn_readlane(apk, 12));
  const h2 O23 = uh((unsigned)__builtin_amdgcn_readlane(apk, 14));
  // ---------- phase C: gate dot2 matvecs (f32 accum) + state update
  const h2 bgf = uh(r.c4.x), bgi = uh(r.c4.y), bgu = uh(r.c4.z),
           bgo = uh(r.c4.w);
  const float fv0 = fdot2f(F01, uh(r.c0.x), fdot2f(F23, uh(r.c0.y), (float)bgf.x));
  const float fv1 = fdot2f(F01, uh(r.c0.z), fdot2f(F23, uh(r.c0.w), (float)bgf.y));
  const float iv0 = fdot2f(I01, uh(r.c1.x), fdot2f(I23, uh(r.c1.y), (float)bgi.x));
  const float iv1 = fdot2f(I01, uh(r.c1.z), fdot2f(I23, uh(r.c1.w), (float)bgi.y));
  const float uv0 = fdot2f(U01, uh(r.c2.x), fdot2f(U23, uh(r.c2.y), (float)bgu.x));
  const float uv1 = fdot2f(U01, uh(r.c2.z), fdot2f(U23, uh(r.c2.w), (float)bgu.y));
  const float ov0 = fdot2f(O01, uh(r.c3.x), fdot2f(O23, uh(r.c3.y), (float)bgo.x));
  const float ov1 = fdot2f(O01, uh(r.c3.z), fdot2f(O23, uh(r.c3.w), (float)bgo.y));
  c0 = fmaf(fv0, c0, iv0 * uv0);
  h0 = ov0 * tanhc(c0);
  c1 = fmaf(fv1, c1, iv1 * uv1);
  h1 = ov1 * tanhc(c1);
  hp = pk2(h0, h1);
  // ---------- reissue this buffer for t+4 (clamped at the tail)
  issue_pf(r, sb, L.jt16 + toff);
  toff = toff + STEPB;
  if (toff > MAXTOFF) toff = MAXTOFF;
}

__device__ __forceinline__ void run_pass(const SBase &sb, const LaneCtx &L,
                                         float4 (*red4)[NW],
                                         const float *yxby_l, float &h0,
                                         float &h1, float &c0, float &c1) {
  Regs R0, R1, R2, R3;
  issue_pf(R0, sb, L.jt16 + 0 * STEPB);
  issue_pf(R1, sb, L.jt16 + 1 * STEPB);
  issue_pf(R2, sb, L.jt16 + 2 * STEPB);
  issue_pf(R3, sb, L.jt16 + 3 * STEPB);
  unsigned toff = 4 * STEPB;
  h2 hp = pk2(0.f, 0.f);
  for (int t = 0; t < Tn; t += 4) {
    qstep<0>(t + 0, R0, toff, sb, L, red4, yxby_l, h0, h1, c0, c1, hp);
    qstep<1>(t + 1, R1, toff, sb, L, red4, yxby_l, h0, h1, c0, c1, hp);
    qstep<0>(t + 2, R2, toff, sb, L, red4, yxby_l, h0, h1, c0, c1, hp);
    qstep<1>(t + 3, R3, toff, sb, L, red4, yxby_l, h0, h1, c0, c1, hp);
  }
  asm volatile("s_waitcnt vmcnt(0)" ::: "memory");
  __builtin_amdgcn_sched_barrier(0);
}

__global__ __launch_bounds__(NTH, 2) void qlstm_f16_kernel(QParams p,
                                                           char *ws) {
  const int b = blockIdx.x;
  LaneCtx L;
  L.tid = threadIdx.x;
  L.lane = L.tid & 63;
  L.wid = L.tid >> 6;
  L.jt16 = (unsigned)L.tid * 16u;
  const int q = L.lane & 3, g = (L.lane >> 2) & 3;
  L.q1 = q & 1;
  L.q2 = q & 2;
  {
    const float *qwp =
        (g == 0) ? p.qw0 : (g == 1) ? p.qw1 : (g == 2) ? p.qw2 : p.qw3;
    L.w4lane = qwp[q];
  }
  L.mlane = (g == 2) ? 2.f : 1.f;
  L.alane = 1.f - L.mlane;
  L.klane = -L.mlane * 1.4426950408889634f;

  __shared__ float4 red4[2][NW];
  __shared__ __align__(16) float yxby_l[Tn * 4];
  __shared__ __align__(16) float hbuf[Hn];

  SBase sbE, sbD;
#pragma unroll
  for (int k = 0; k < 6; ++k) {
    sbE.a[k] = (unsigned long long)ws + (unsigned long long)k * 8192ull;
    sbD.a[k] = (unsigned long long)ws + REC_PASS + (unsigned long long)k * 8192ull;
  }

  // ---- encoder prologue: stage yx(+by) table
  ((float4 *)yxby_l)[L.tid] =
      ((const float4 *)(ws + YXE_OFF))[(size_t)b * Tn + L.tid];
  float h0 = 0.f, h1 = 0.f, c0 = 0.f, c1 = 0.f;
  __syncthreads();

  run_pass(sbE, L, red4, yxby_l, h0, h1, c0, c1);

  // ---- transition: stage h_enc, build decoder yx table
  __syncthreads();
  hbuf[L.tid] = h0;
  hbuf[L.tid + NTH] = h1;
  __syncthreads();
  {
    const float hv = hbuf[L.tid]; // = h_enc[t] for t = tid
    const float4 wx =
        *(const float4 *)(p.Wy_d + ((size_t)L.tid * (Hn + 1) + Hn) * 4);
    const float4 bd = *(const float4 *)(p.by_d + L.tid * 4);
    ((float4 *)yxby_l)[L.tid] =
        make_float4(fmaf(hv, wx.x, bd.x), fmaf(hv, wx.y, bd.y),
                    fmaf(hv, wx.z, bd.z), fmaf(hv, wx.w, bd.w));
  }
  h0 = h1 = c0 = c1 = 0.f;
  __syncthreads();

  run_pass(sbD, L, red4, yxby_l, h0, h1, c0, c1);

  // ---- projection: out[b][t] = h_dec @ Wt[:,t] + bt[t]
  __syncthreads();
  hbuf[L.tid] = h0;
  hbuf[L.tid + NTH] = h1;
  __syncthreads();
  {
    float acc = p.bt[L.tid];
    const float4 *h4 = (const float4 *)hbuf;
#pragma unroll 4
    for (int j4 = 0; j4 < Hn / 4; ++j4) {
      const float4 hv = h4[j4];
      acc = fmaf(hv.x, p.Wt[(j4 * 4 + 0) * Tn + L.tid], acc);
      acc = fmaf(hv.y, p.Wt[(j4 * 4 + 1) * Tn + L.tid], acc);
      acc = fmaf(hv.z, p.Wt[(j4 * 4 + 2) * Tn + L.tid], acc);
      acc = fmaf(hv.w, p.Wt[(j4 * 4 + 3) * Tn + L.tid], acc);
    }
    p.out[(size_t)b * Tn + L.tid] = acc;
  }
}

// =============================================================================
// Fallback (round-3 f32 kernel): used only if ws_size < WS_NEED.
// =============================================================================
struct WB {
  float w[32];
  float bb[8];
  float4 wy0, wy1;
  float4 wyx;
  float xv;
};

template <bool DEC>
__device__ __forceinline__ WB
pf_fb(int t, int b, int tid, const float *__restrict__ x,
      const float *__restrict__ Wy, const float *__restrict__ Wf,
      const float *__restrict__ bfp, const float *__restrict__ Wi,
      const float *__restrict__ bip, const float *__restrict__ Wu,
      const float *__restrict__ bup, const float *__restrict__ Wo,
      const float *__restrict__ bop) {
  WB d;
  const int K = DEC ? (Hn + 1) : (Hn + Fn);
  const int g0 = t * 4096 + tid;
#pragma unroll
  for (int e = 0; e < 2; ++e) {
    const int ge = g0 + e * 512;
#pragma unroll
    for (int n = 0; n < 4; ++n) {
      d.w[e * 16 + 0 * 4 + n] = Wf[ge + n * 1024];
      d.w[e * 16 + 1 * 4 + n] = Wi[ge + n * 1024];
      d.w[e * 16 + 2 * 4 + n] = Wu[ge + n * 1024];
      d.w[e * 16 + 3 * 4 + n] = Wo[ge + n * 1024];
    }
    const int be = t * 1024 + tid + e * 512;
    d.bb[e * 4 + 0] = bfp[be];
    d.bb[e * 4 + 1] = bip[be];
    d.bb[e * 4 + 2] = bup[be];
    d.bb[e * 4 + 3] = bop[be];
  }
  d.wy0 = *(const float4 *)(Wy + (t * K + tid) * 4);
  d.wy1 = *(const float4 *)(Wy + (t * K + tid + 512) * 4);
  if (!DEC) {
    if (tid < Fn) {
      d.wyx = *(const float4 *)(Wy + (t * K + Hn + tid) * 4);
      d.xv = x[(b * Tn + t) * Fn + tid];
    }
  } else {
    if (tid == 0) d.wyx = *(const float4 *)(Wy + (t * K + Hn) * 4);
  }
  return d;
}

template <bool DEC, int PAR>
__device__ __forceinline__ void
step_fb(int t, int tn, const WB &rd, WB &wr, int b, const LaneCtx &L,
        const float *__restrict__ x, const float *__restrict__ Wy,
        const float *__restrict__ Wf, const float *__restrict__ bfp,
        const float *__restrict__ Wi, const float *__restrict__ bip,
        const float *__restrict__ Wu, const float *__restrict__ bup,
        const float *__restrict__ Wo, const float *__restrict__ bop,
        float4 (*red4)[NW], const float *by_l, const float *henc_s, float &h0,
        float &h1, float &c0, float &c1) {
  float a0 = h0 * rd.wy0.x, a1 = h0 * rd.wy0.y, a2 = h0 * rd.wy0.z,
        a3 = h0 * rd.wy0.w;
  a0 = fmaf(h1, rd.wy1.x, a0);
  a1 = fmaf(h1, rd.wy1.y, a1);
  a2 = fmaf(h1, rd.wy1.z, a2);
  a3 = fmaf(h1, rd.wy1.w, a3);
  if (!DEC) {
    if (L.tid < Fn) {
      a0 = fmaf(rd.xv, rd.wyx.x, a0);
      a1 = fmaf(rd.xv, rd.wyx.y, a1);
      a2 = fmaf(rd.xv, rd.wyx.z, a2);
      a3 = fmaf(rd.xv, rd.wyx.w, a3);
    }
  } else {
    if (L.tid == 0) {
      const float xv = henc_s[t];
      a0 = fmaf(xv, rd.wyx.x, a0);
      a1 = fmaf(xv, rd.wyx.y, a1);
      a2 = fmaf(xv, rd.wyx.z, a2);
      a3 = fmaf(xv, rd.wyx.w, a3);
    }
  }
  a0 = wave_sum63(a0);
  a1 = wave_sum63(a1);
  a2 = wave_sum63(a2);
  a3 = wave_sum63(a3);
  if (L.lane == 63) red4[PAR][L.wid] = make_float4(a0, a1, a2, a3);
  wr = pf_fb<DEC>(tn, b, L.tid, x, Wy, Wf, bfp, Wi, bip, Wu, bup, Wo, bop);
  BAR();
  float4 rv = red4[PAR][L.lane & 7];
  const float byq = by_l[t * 4 + (L.lane & 3)];
  float y0 = sum8_all(rv.x), y1 = sum8_all(rv.y), y2 = sum8_all(rv.z),
        y3 = sum8_all(rv.w);
  const float yq = L.q2 ? (L.q1 ? y3 : y2) : (L.q1 ? y1 : y0);
  const float ang = yq + byq + L.w4lane;
  const float cc = __cosf(ang);
  const float t1 = dppmov<0xB1>(cc);
  const float d1 = cc * t1;
  const float t2 = dppmov<0x4E>(d1);
  const float d2 = d1 * t2;
  const float zu = t1 * t2;
  const float zv = cc * t2;
  const float z = L.q2 ? (L.q1 ? d2 : zv) : (L.q1 ? d1 : zu);
  const float s =
      __builtin_amdgcn_rcpf(1.f + __builtin_amdgcn_exp2f(L.klane * z));
  const float act = fmaf(s, L.mlane, L.alane);
#define RL(n)                                                                  \
  __builtin_bit_cast(float,                                                    \
                     __builtin_amdgcn_readlane(__builtin_bit_cast(int, act), n))
  const float f0 = RL(0), f1 = RL(1), f2 = RL(2), f3 = RL(3);
  const float i0 = RL(4), i1 = RL(5), i2 = RL(6), i3 = RL(7);
  const float u0 = RL(8), u1 = RL(9), u2 = RL(10), u3 = RL(11);
  const float o0 = RL(12), o1 = RL(13), o2 = RL(14), o3 = RL(15);
#undef RL
#pragma unroll
  for (int e = 0; e < 2; ++e) {
    float fv = rd.bb[e * 4 + 0], iv = rd.bb[e * 4 + 1], uv = rd.bb[e * 4 + 2],
          ov = rd.bb[e * 4 + 3];
    fv = fmaf(f0, rd.w[e * 16 + 0], fv);
    fv = fmaf(f1, rd.w[e * 16 + 1], fv);
    fv = fmaf(f2, rd.w[e * 16 + 2], fv);
    fv = fmaf(f3, rd.w[e * 16 + 3], fv);
    iv = fmaf(i0, rd.w[e * 16 + 4], iv);
    iv = fmaf(i1, rd.w[e * 16 + 5], iv);
    iv = fmaf(i2, rd.w[e * 16 + 6], iv);
    iv = fmaf(i3, rd.w[e * 16 + 7], iv);
    uv = fmaf(u0, rd.w[e * 16 + 8], uv);
    uv = fmaf(u1, rd.w[e * 16 + 9], uv);
    uv = fmaf(u2, rd.w[e * 16 + 10], uv);
    uv = fmaf(u3, rd.w[e * 16 + 11], uv);
    ov = fmaf(o0, rd.w[e * 16 + 12], ov);
    ov = fmaf(o1, rd.w[e * 16 + 13], ov);
    ov = fmaf(o2, rd.w[e * 16 + 14], ov);
    ov = fmaf(o3, rd.w[e * 16 + 15], ov);
    float &cr = e ? c1 : c0;
    float &hr = e ? h1 : h0;
    const float cn = fmaf(fv, cr, iv * uv);
    cr = cn;
    hr = ov * tanhc(cn);
  }
}

template <bool DEC>
__device__ void lstm_pass_fb(int b, const LaneCtx &L,
                             const float *__restrict__ x,
                             const float *__restrict__ Wy,
                             const float *__restrict__ by,
                             const float *__restrict__ Wf,
                             const float *__restrict__ bfp,
                             const float *__restrict__ Wi,
                             const float *__restrict__ bip,
                             const float *__restrict__ Wu,
                             const float *__restrict__ bup,
                             const float *__restrict__ Wo,
                             const float *__restrict__ bop,
                             float4 (*red4)[NW], float *by_l,
                             const float *henc_s, float &h0, float &h1,
                             float &c0, float &c1) {
#pragma unroll
  for (int i = 0; i < (Tn * 4) / NTH; ++i)
    by_l[L.tid + i * NTH] = by[L.tid + i * NTH];
  __syncthreads();
  WB bufA = pf_fb<DEC>(0, b, L.tid, x, Wy, Wf, bfp, Wi, bip, Wu, bup, Wo, bop);
  WB bufB;
  for (int t = 0; t < Tn; t += 2) {
    step_fb<DEC, 0>(t, t + 1, bufA, bufB, b, L, x, Wy, Wf, bfp, Wi, bip, Wu,
                    bup, Wo, bop, red4, by_l, henc_s, h0, h1, c0, c1);
    step_fb<DEC, 1>(t + 1, (t + 2 < Tn) ? (t + 2) : (Tn - 1), bufB, bufA, b, L,
                    x, Wy, Wf, bfp, Wi, bip, Wu, bup, Wo, bop, red4, by_l,
                    henc_s, h0, h1, c0, c1);
  }
}

__global__ __launch_bounds__(NTH, 2) void qlstm_fb_kernel(QParams p) {
  const int b = blockIdx.x;
  LaneCtx L;
  L.tid = threadIdx.x;
  L.lane = L.tid & 63;
  L.wid = L.tid >> 6;
  L.jt16 = (unsigned)L.tid * 16u;
  const int q = L.lane & 3, g = (L.lane >> 2) & 3;
  L.q1 = q & 1;
  L.q2 = q & 2;
  {
    const float *qwp =
        (g == 0) ? p.qw0 : (g == 1) ? p.qw1 : (g == 2) ? p.qw2 : p.qw3;
    L.w4lane = qwp[q];
  }
  L.mlane = (g == 2) ? 2.f : 1.f;
  L.alane = 1.f - L.mlane;
  L.klane = -L.mlane * 1.4426950408889634f;

  __shared__ float4 red4[2][NW];
  __shared__ float by_l[Tn * 4];
  __shared__ float henc_s[Hn];
  __shared__ float hst[Hn];

  float h0 = 0.f, h1 = 0.f, c0 = 0.f, c1 = 0.f;

  lstm_pass_fb<false>(b, L, p.x, p.Wy_e, p.by_e, p.Wf_e, p.bf_e, p.Wi_e,
                      p.bi_e, p.Wu_e, p.bu_e, p.Wo_e, p.bo_e, red4, by_l,
                      henc_s, h0, h1, c0, c1);
  henc_s[L.tid] = h0;
  henc_s[L.tid + NTH] = h1;
  h0 = h1 = c0 = c1 = 0.f;
  __syncthreads();
  lstm_pass_fb<true>(b, L, nullptr, p.Wy_d, p.by_d, p.Wf_d, p.bf_d, p.Wi_d,
                     p.bi_d, p.Wu_d, p.bu_d, p.Wo_d, p.bo_d, red4, by_l,
                     henc_s, h0, h1, c0, c1);
  hst[L.tid] = h0;
  hst[L.tid + NTH] = h1;
  __syncthreads();
  {
    float acc = p.bt[L.tid];
    const float4 *h4 = (const float4 *)hst;
#pragma unroll 4
    for (int j4 = 0; j4 < Hn / 4; ++j4) {
      const float4 hv = h4[j4];
      acc = fmaf(hv.x, p.Wt[(j4 * 4 + 0) * Tn + L.tid], acc);
      acc = fmaf(hv.y, p.Wt[(j4 * 4 + 1) * Tn + L.tid], acc);
      acc = fmaf(hv.z, p.Wt[(j4 * 4 + 2) * Tn + L.tid], acc);
      acc = fmaf(hv.w, p.Wt[(j4 * 4 + 3) * Tn + L.tid], acc);
    }
    p.out[(size_t)b * Tn + L.tid] = acc;
  }
}

extern "C" void kernel_launch(void *const *d_in, const int *in_sizes, int n_in,
                              void *d_out, int out_size, void *d_ws,
                              size_t ws_size, hipStream_t stream) {
  QParams p;
  p.x = (const float *)d_in[0];
  p.qw0 = (const float *)d_in[1];
  p.qw1 = (const float *)d_in[2];
  p.qw2 = (const float *)d_in[3];
  p.qw3 = (const float *)d_in[4];
  p.Wy_e = (const float *)d_in[5];
  p.by_e = (const float *)d_in[6];
  p.Wf_e = (const float *)d_in[7];
  p.bf_e = (const float *)d_in[8];
  p.Wi_e = (const float *)d_in[9];
  p.bi_e = (const float *)d_in[10];
  p.Wu_e = (const float *)d_in[11];
  p.bu_e = (const float *)d_in[12];
  p.Wo_e = (const float *)d_in[13];
  p.bo_e = (const float *)d_in[14];
  p.Wy_d = (const float *)d_in[15];
  p.by_d = (const float *)d_in[16];
  p.Wf_d = (const float *)d_in[17];
  p.bf_d = (const float *)d_in[18];
  p.Wi_d = (const float *)d_in[19];
  p.bi_d = (const float *)d_in[20];
  p.Wu_d = (const float *)d_in[21];
  p.bu_d = (const float *)d_in[22];
  p.Wo_d = (const float *)d_in[23];
  p.bo_d = (const float *)d_in[24];
  p.Wt = (const float *)d_in[25];
  p.bt = (const float *)d_in[26];
  p.out = (float *)d_out;

  if (ws_size >= WS_NEED) {
    char *ws = (char *)d_ws;
    hipLaunchKernelGGL(qprep_kernel, dim3(1024), dim3(512), 0, stream, p, ws);
    hipLaunchKernelGGL(qlstm_f16_kernel, dim3(16), dim3(NTH), 0, stream, p,
                       ws);
  } else {
    hipLaunchKernelGGL(qlstm_fb_kernel, dim3(16), dim3(NTH), 0, stream, p);
  }
}